// Round 1
// baseline (828.436 us; speedup 1.0000x reference)
//
#include <hip/hip_runtime.h>
#include <hip/hip_bf16.h>
#include <stdint.h>

typedef __hip_bfloat16 bf16;
typedef __attribute__((ext_vector_type(8))) short bf16x8_t;
typedef __attribute__((ext_vector_type(4))) float f32x4_t;

#define B_ 4
#define T_ 2048
#define D_ 1024
#define H_ 16
#define HS_ 64

// ---------------------------------------------------------------- helpers
__device__ __forceinline__ void gload_lds16(const void* g, void* l) {
    __builtin_amdgcn_global_load_lds(
        (const __attribute__((address_space(1))) unsigned int*)g,
        (__attribute__((address_space(3))) unsigned int*)l, 16, 0, 0);
}

__device__ __forceinline__ bf16x8_t ldsv8(const bf16* p) {
    return *(const bf16x8_t*)p;
}

// ---------------------------------------------------------------- weight transpose + fp32->bf16
// W[K,N] fp32 -> WT[N,K] bf16
__global__ __launch_bounds__(256) void transpose_cvt(
    const float* __restrict__ W, bf16* __restrict__ WT, int K, int N)
{
    __shared__ float tile[32][33];
    const int nbx = N >> 5;
    const int bx = blockIdx.x % nbx;   // n-tile
    const int by = blockIdx.x / nbx;   // k-tile
    const int n0 = bx << 5, k0 = by << 5;
    const int tx = threadIdx.x & 31, ty = threadIdx.x >> 5;  // ty 0..7
#pragma unroll
    for (int i = 0; i < 32; i += 8)
        tile[ty + i][tx] = W[(long)(k0 + ty + i) * N + n0 + tx];
    __syncthreads();
#pragma unroll
    for (int i = 0; i < 32; i += 8)
        WT[(long)(n0 + ty + i) * K + k0 + tx] = __float2bfloat16(tile[tx][ty + i]);
}

// ---------------------------------------------------------------- LayerNorm (fp32 in -> bf16 out)
__global__ __launch_bounds__(256) void ln_k(
    const float* __restrict__ x, const float* __restrict__ g,
    const float* __restrict__ be, bf16* __restrict__ out)
{
    const long row = blockIdx.x;
    const int t = threadIdx.x;
    const float4 v = ((const float4*)(x + row * D_))[t];
    float s  = v.x + v.y + v.z + v.w;
    float s2 = v.x * v.x + v.y * v.y + v.z * v.z + v.w * v.w;
#pragma unroll
    for (int m = 1; m < 64; m <<= 1) {
        s  += __shfl_xor(s, m, 64);
        s2 += __shfl_xor(s2, m, 64);
    }
    __shared__ float red[8];
    const int wv = t >> 6, ln = t & 63;
    if (ln == 0) { red[wv] = s; red[4 + wv] = s2; }
    __syncthreads();
    s  = red[0] + red[1] + red[2] + red[3];
    s2 = red[4] + red[5] + red[6] + red[7];
    const float mu  = s * (1.f / (float)D_);
    const float var = s2 * (1.f / (float)D_) - mu * mu;
    const float rs  = rsqrtf(var + 1e-5f);
    const float4 gv = ((const float4*)g)[t];
    const float4 bv = ((const float4*)be)[t];
    union { bf16 h[4]; short4 s4; } u;
    u.h[0] = __float2bfloat16((v.x - mu) * rs * gv.x + bv.x);
    u.h[1] = __float2bfloat16((v.y - mu) * rs * gv.y + bv.y);
    u.h[2] = __float2bfloat16((v.z - mu) * rs * gv.z + bv.z);
    u.h[3] = __float2bfloat16((v.w - mu) * rs * gv.w + bv.w);
    ((short4*)(out + row * D_))[t] = u.s4;
}

// ---------------------------------------------------------------- GEMM: C[M,N] = A[M,K] @ BT[N,K]^T
// A bf16 row-major [M,K]; BT bf16 row-major [N,K] (i.e. B transposed).
// Epilogue: optional fp32 bias[N], ReLU, fp32 residual[M,N]; out bf16 or fp32.
template<int HAS_BIAS, int RELU, int HAS_RES, int OUT_BF16>
__global__ __launch_bounds__(256, 2) void gemm_bt(
    const bf16* __restrict__ A, const bf16* __restrict__ BT,
    const float* __restrict__ bias, const float* __restrict__ res,
    void* __restrict__ Cout, int M, int N, int K)
{
    __shared__ bf16 As[128 * 32];
    __shared__ bf16 Bs[128 * 32];
    const int tid  = threadIdx.x;
    const int wave = tid >> 6;
    const int lane = tid & 63;
    const int nbn  = N >> 7;
    const int bm = blockIdx.x / nbn;
    const int bn = blockIdx.x % nbn;
    const int row0 = bm << 7, col0 = bn << 7;
    const int wm = wave & 1, wn = wave >> 1;   // wave tile: rows wm*64, cols wn*64

    // staging: thread t loads 16B: row t/4 (0..63), col (t%4)*8 of a [128][32] tile
    const int srow = tid >> 2;
    const int scol = (tid & 3) << 3;
    const bf16* aSrc = A  + (long)(row0 + srow) * K + scol;
    const bf16* bSrc = BT + (long)(col0 + srow) * K + scol;
    bf16* aDst1 = As + wave * 512;
    bf16* aDst2 = As + 2048 + wave * 512;
    bf16* bDst1 = Bs + wave * 512;
    bf16* bDst2 = Bs + 2048 + wave * 512;

    f32x4_t acc[4][4] = {};

    const int fr = lane & 15;          // fragment row
    const int fk = (lane >> 4) << 3;   // fragment k-offset

    for (int k0 = 0; k0 < K; k0 += 32) {
        gload_lds16(aSrc + k0, aDst1);
        gload_lds16(aSrc + k0 + (long)64 * K, aDst2);
        gload_lds16(bSrc + k0, bDst1);
        gload_lds16(bSrc + k0 + (long)64 * K, bDst2);
        __syncthreads();   // drains vmcnt: LDS tiles ready
        bf16x8_t a[4], b[4];
#pragma unroll
        for (int m = 0; m < 4; ++m)
            a[m] = ldsv8(As + (wm * 64 + m * 16 + fr) * 32 + fk);
#pragma unroll
        for (int n = 0; n < 4; ++n)
            b[n] = ldsv8(Bs + (wn * 64 + n * 16 + fr) * 32 + fk);
#pragma unroll
        for (int m = 0; m < 4; ++m)
#pragma unroll
            for (int n = 0; n < 4; ++n)
                acc[m][n] = __builtin_amdgcn_mfma_f32_16x16x32_bf16(a[m], b[n], acc[m][n], 0, 0, 0);
        __syncthreads();   // all reads done before next stage overwrites
    }

    // epilogue: D layout col=lane&15, row=(lane>>4)*4+reg  [measured m89/m91]
    const int orow = (lane >> 4) << 2;
#pragma unroll
    for (int m = 0; m < 4; ++m) {
        const int rbase = row0 + wm * 64 + m * 16 + orow;
#pragma unroll
        for (int n = 0; n < 4; ++n) {
            const int c = col0 + wn * 64 + n * 16 + fr;
            float bv = 0.f;
            if (HAS_BIAS) bv = bias[c];
#pragma unroll
            for (int r = 0; r < 4; ++r) {
                float v = acc[m][n][r] + bv;
                if (RELU) v = fmaxf(v, 0.f);
                if (HAS_RES) v += res[(long)(rbase + r) * N + c];
                if (OUT_BF16)
                    ((bf16*)Cout)[(long)(rbase + r) * N + c] = __float2bfloat16(v);
                else
                    ((float*)Cout)[(long)(rbase + r) * N + c] = v;
            }
        }
    }
}

// ---------------------------------------------------------------- flash attention (causal)
// Q,K,V,O: bf16 [B*T, D], head h occupies cols h*64..h*64+63.
// grid: (T/64, B*H). Block: 256 threads = 4 waves, wave w handles 16 q-rows.
__global__ __launch_bounds__(256, 2) void attn_flash(
    const bf16* __restrict__ Q, const bf16* __restrict__ Kg,
    const bf16* __restrict__ Vg, bf16* __restrict__ O)
{
    __shared__ bf16 Ks[64 * 64];    // K-tile row-major [kr][hs]
    __shared__ bf16 Vts[64 * 64];   // V-tile transposed [hs][kr]
    __shared__ bf16 Ps[4 * 16 * 64];// per-wave P [16 q][64 kr]

    const int tid = threadIdx.x;
    const int wave = tid >> 6, lane = tid & 63;
    const int fr = lane & 15, fk = (lane >> 4) << 3;
    const int orow = (lane >> 4) << 2;

    const int qt = blockIdx.x;          // q-tile (64 rows)
    const int bh = blockIdx.y;
    const int b = bh >> 4, h = bh & 15;
    const long rowBase = (long)b * T_;
    const int colBase = h * HS_;

    // Q fragments (A-operand): lane holds Q[q=fr][hs=fk..fk+7] per 32-slice
    const long qrow = rowBase + qt * 64 + wave * 16 + fr;
    bf16x8_t qf[2];
    qf[0] = *(const bf16x8_t*)(Q + qrow * D_ + colBase + fk);
    qf[1] = *(const bf16x8_t*)(Q + qrow * D_ + colBase + 32 + fk);

    f32x4_t o[4] = {};
    float mOld[4], lOld[4];
#pragma unroll
    for (int r = 0; r < 4; ++r) { mOld[r] = -1e30f; lOld[r] = 0.f; }

    const int svr = tid >> 3;            // 0..31 (row), 8 threads/row
    const int svc = (tid & 7) << 3;      // hs offset
    bf16* kDst1 = Ks + wave * 512;
    bf16* kDst2 = Ks + 2048 + wave * 512;
    bf16* Pw = Ps + wave * 1024;

    for (int c = 0; c <= qt; ++c) {
        const long krow = rowBase + c * 64;
        // K tile -> LDS linear (global_load_lds, 2 half-tiles)
        gload_lds16(Kg + (krow + svr) * D_ + colBase + svc, kDst1);
        gload_lds16(Kg + (krow + 32 + svr) * D_ + colBase + svc, kDst2);
        // V tile -> LDS transposed (reg-staged)
        {
            union { bf16x8_t v; bf16 hh[8]; } u1, u2;
            u1.v = *(const bf16x8_t*)(Vg + (krow + svr) * D_ + colBase + svc);
            u2.v = *(const bf16x8_t*)(Vg + (krow + 32 + svr) * D_ + colBase + svc);
#pragma unroll
            for (int i = 0; i < 8; ++i) {
                Vts[(svc + i) * 64 + svr] = u1.hh[i];
                Vts[(svc + i) * 64 + 32 + svr] = u2.hh[i];
            }
        }
        __syncthreads();

        // S = Q K^T  (S[q][kr], 16x64 per wave as 4 col-tiles)
        f32x4_t s[4] = {};
#pragma unroll
        for (int kk = 0; kk < 4; ++kk) {
            bf16x8_t kf0 = ldsv8(Ks + (kk * 16 + fr) * 64 + fk);
            bf16x8_t kf1 = ldsv8(Ks + (kk * 16 + fr) * 64 + 32 + fk);
            s[kk] = __builtin_amdgcn_mfma_f32_16x16x32_bf16(qf[0], kf0, s[kk], 0, 0, 0);
            s[kk] = __builtin_amdgcn_mfma_f32_16x16x32_bf16(qf[1], kf1, s[kk], 0, 0, 0);
        }

        // scale (D^-0.5 = 1/32), causal mask, online softmax
        const int qrel = qt * 64 + wave * 16 + orow;   // + r = absolute q
        float p[4][4];
#pragma unroll
        for (int r = 0; r < 4; ++r) {
            float rm = -1e30f;
#pragma unroll
            for (int kk = 0; kk < 4; ++kk) {
                float sv = s[kk][r] * 0.03125f;
                const int kabs = c * 64 + kk * 16 + fr;
                if (c == qt && kabs > qrel + r) sv = -1e30f;
                p[kk][r] = sv;
                rm = fmaxf(rm, sv);
            }
#pragma unroll
            for (int mm = 1; mm < 16; mm <<= 1)
                rm = fmaxf(rm, __shfl_xor(rm, mm, 64));
            const float mNew = fmaxf(mOld[r], rm);
            const float corr = __expf(mOld[r] - mNew);
            float rsum = 0.f;
#pragma unroll
            for (int kk = 0; kk < 4; ++kk) {
                const float pe = __expf(p[kk][r] - mNew);
                p[kk][r] = pe;
                rsum += pe;
            }
#pragma unroll
            for (int mm = 1; mm < 16; mm <<= 1)
                rsum += __shfl_xor(rsum, mm, 64);
            lOld[r] = lOld[r] * corr + rsum;
            mOld[r] = mNew;
#pragma unroll
            for (int n = 0; n < 4; ++n) o[n][r] *= corr;
        }

        // P -> LDS (D-layout -> A-layout repack)
#pragma unroll
        for (int kk = 0; kk < 4; ++kk)
#pragma unroll
            for (int r = 0; r < 4; ++r)
                Pw[(orow + r) * 64 + kk * 16 + fr] = __float2bfloat16(p[kk][r]);
        __syncthreads();

        // O += P V
#pragma unroll
        for (int ks = 0; ks < 2; ++ks) {
            bf16x8_t pa = ldsv8(Pw + fr * 64 + ks * 32 + fk);
#pragma unroll
            for (int n = 0; n < 4; ++n) {
                bf16x8_t vf = ldsv8(Vts + (n * 16 + fr) * 64 + ks * 32 + fk);
                o[n] = __builtin_amdgcn_mfma_f32_16x16x32_bf16(pa, vf, o[n], 0, 0, 0);
            }
        }
        __syncthreads();   // protect K/V/P LDS before next iteration's staging
    }

    // normalize + store
    const long orowg = rowBase + qt * 64 + wave * 16 + orow;
#pragma unroll
    for (int n = 0; n < 4; ++n) {
        const int cg = colBase + n * 16 + fr;
#pragma unroll
        for (int r = 0; r < 4; ++r)
            O[(orowg + r) * D_ + cg] = __float2bfloat16(o[n][r] / lOld[r]);
    }
}

// ---------------------------------------------------------------- launch
extern "C" void kernel_launch(void* const* d_in, const int* in_sizes, int n_in,
                              void* d_out, int out_size, void* d_ws, size_t ws_size,
                              hipStream_t stream)
{
    (void)in_sizes; (void)n_in; (void)out_size; (void)ws_size;
    const float* x   = (const float*)d_in[0];
    const float* wq  = (const float*)d_in[1];
    const float* wk  = (const float*)d_in[2];
    const float* wv  = (const float*)d_in[3];
    const float* wo  = (const float*)d_in[4];
    const float* bo  = (const float*)d_in[5];
    const float* w1  = (const float*)d_in[6];
    const float* b1  = (const float*)d_in[7];
    const float* w2  = (const float*)d_in[8];
    const float* b2  = (const float*)d_in[9];
    const float* g1  = (const float*)d_in[10];
    const float* be1 = (const float*)d_in[11];
    const float* g2  = (const float*)d_in[12];
    const float* be2 = (const float*)d_in[13];
    float* out = (float*)d_out;

    char* ws = (char*)d_ws;
    const size_t SLOT = (size_t)8192 * 1024 * 2;   // 16MB bf16 [8192,1024]
    // slot reuse plan:
    //  slot0: xn   -> attnb      slot1: qb -> xn2
    //  slot2..5: kb, vb, --, --  -> hidden (64MB spanning slots 2..5)
    bf16* xn     = (bf16*)(ws);
    bf16* attnb  = (bf16*)(ws);                    // reuse after QKV GEMMs
    bf16* qb     = (bf16*)(ws + SLOT);
    bf16* xn2    = (bf16*)(ws + SLOT);             // reuse after attention
    bf16* kb     = (bf16*)(ws + 2 * SLOT);
    bf16* vb     = (bf16*)(ws + 3 * SLOT);
    bf16* hidden = (bf16*)(ws + 2 * SLOT);         // 64MB, slots 2..5 (kb/vb dead)
    float* x1    = (float*)(ws + 6 * SLOT);        // 32MB fp32
    char* wpos   = ws + 6 * SLOT + (size_t)33554432;
    bf16* wqT = (bf16*)(wpos);
    bf16* wkT = (bf16*)(wpos + (size_t)2097152);
    bf16* wvT = (bf16*)(wpos + (size_t)2 * 2097152);
    bf16* woT = (bf16*)(wpos + (size_t)3 * 2097152);
    bf16* w1T = (bf16*)(wpos + (size_t)4 * 2097152);
    bf16* w2T = (bf16*)(wpos + (size_t)4 * 2097152 + 8388608);

    // weights: fp32 [K,N] -> bf16 [N,K]
    transpose_cvt<<<dim3(1024), 256, 0, stream>>>(wq, wqT, 1024, 1024);
    transpose_cvt<<<dim3(1024), 256, 0, stream>>>(wk, wkT, 1024, 1024);
    transpose_cvt<<<dim3(1024), 256, 0, stream>>>(wv, wvT, 1024, 1024);
    transpose_cvt<<<dim3(1024), 256, 0, stream>>>(wo, woT, 1024, 1024);
    transpose_cvt<<<dim3(4096), 256, 0, stream>>>(w1, w1T, 1024, 4096);
    transpose_cvt<<<dim3(4096), 256, 0, stream>>>(w2, w2T, 4096, 1024);

    // LN1
    ln_k<<<8192, 256, 0, stream>>>(x, g1, be1, xn);

    // QKV
    gemm_bt<0, 0, 0, 1><<<512, 256, 0, stream>>>(xn, wqT, nullptr, nullptr, qb, 8192, 1024, 1024);
    gemm_bt<0, 0, 0, 1><<<512, 256, 0, stream>>>(xn, wkT, nullptr, nullptr, kb, 8192, 1024, 1024);
    gemm_bt<0, 0, 0, 1><<<512, 256, 0, stream>>>(xn, wvT, nullptr, nullptr, vb, 8192, 1024, 1024);

    // attention (writes attnb = slot0; xn dead by now)
    attn_flash<<<dim3(32, 64), 256, 0, stream>>>(qb, kb, vb, attnb);

    // x1 = x + attn @ wo + bo
    gemm_bt<1, 0, 1, 0><<<512, 256, 0, stream>>>(attnb, woT, bo, x, x1, 8192, 1024, 1024);

    // LN2 (xn2 = slot1; qb dead)
    ln_k<<<8192, 256, 0, stream>>>(x1, g2, be2, xn2);

    // hidden = relu(xn2 @ w1 + b1)   (hidden spans slots 2..5; kb/vb dead)
    gemm_bt<1, 1, 0, 1><<<2048, 256, 0, stream>>>(xn2, w1T, b1, nullptr, hidden, 8192, 4096, 1024);

    // out = x1 + hidden @ w2 + b2
    gemm_bt<1, 0, 1, 0><<<512, 256, 0, stream>>>(hidden, w2T, b2, x1, out, 8192, 1024, 4096);
}

// Round 2
// 662.229 us; speedup vs baseline: 1.2510x; 1.2510x over previous
//
#include <hip/hip_runtime.h>
#include <hip/hip_bf16.h>
#include <stdint.h>

typedef __hip_bfloat16 bf16;
typedef __attribute__((ext_vector_type(8))) short bf16x8_t;
typedef __attribute__((ext_vector_type(4))) float f32x4_t;

#define B_ 4
#define T_ 2048
#define D_ 1024
#define H_ 16
#define HS_ 64

// ---------------------------------------------------------------- helpers
__device__ __forceinline__ void gload_lds16(const void* g, void* l) {
    __builtin_amdgcn_global_load_lds(
        (const __attribute__((address_space(1))) unsigned int*)g,
        (__attribute__((address_space(3))) unsigned int*)l, 16, 0, 0);
}

__device__ __forceinline__ bf16x8_t ldsv8(const bf16* p) {
    return *(const bf16x8_t*)p;
}

// ---------------------------------------------------------------- weight transpose + fp32->bf16
// W[K,N] fp32 -> WT[N,K] bf16
__global__ __launch_bounds__(256) void transpose_cvt(
    const float* __restrict__ W, bf16* __restrict__ WT, int K, int N)
{
    __shared__ float tile[32][33];
    const int nbx = N >> 5;
    const int bx = blockIdx.x % nbx;   // n-tile
    const int by = blockIdx.x / nbx;   // k-tile
    const int n0 = bx << 5, k0 = by << 5;
    const int tx = threadIdx.x & 31, ty = threadIdx.x >> 5;  // ty 0..7
#pragma unroll
    for (int i = 0; i < 32; i += 8)
        tile[ty + i][tx] = W[(long)(k0 + ty + i) * N + n0 + tx];
    __syncthreads();
#pragma unroll
    for (int i = 0; i < 32; i += 8)
        WT[(long)(n0 + ty + i) * K + k0 + tx] = __float2bfloat16(tile[tx][ty + i]);
}

// ---------------------------------------------------------------- per-head V transpose (bf16)
// V [B*T, D] -> VT [B*H*HS, T]  (row = bh*64+hs, col = t)
__global__ __launch_bounds__(256) void vhead_transpose(
    const bf16* __restrict__ V, bf16* __restrict__ VT)
{
    __shared__ bf16 tile[32][33];
    int idx = blockIdx.x;
    const int tt  = idx & 63;   idx >>= 6;   // t-tile (T/32 = 64)
    const int hst = idx & 1;    idx >>= 1;   // hs-tile (HS/32 = 2)
    const int bh  = idx;                     // 0..63
    const int b = bh >> 4, h = bh & 15;
    const int tx = threadIdx.x & 31, ty = threadIdx.x >> 5;
    const long vrow = (long)b * T_ + tt * 32;
    const int  vcol = h * HS_ + hst * 32;
#pragma unroll
    for (int i = 0; i < 32; i += 8)
        tile[ty + i][tx] = V[(vrow + ty + i) * D_ + vcol + tx];
    __syncthreads();
    const long orow = (long)bh * HS_ + hst * 32;
#pragma unroll
    for (int i = 0; i < 32; i += 8)
        VT[(orow + ty + i) * T_ + tt * 32 + tx] = tile[tx][ty + i];
}

// ---------------------------------------------------------------- LayerNorm (fp32 in -> bf16 out)
__global__ __launch_bounds__(256) void ln_k(
    const float* __restrict__ x, const float* __restrict__ g,
    const float* __restrict__ be, bf16* __restrict__ out)
{
    const long row = blockIdx.x;
    const int t = threadIdx.x;
    const float4 v = ((const float4*)(x + row * D_))[t];
    float s  = v.x + v.y + v.z + v.w;
    float s2 = v.x * v.x + v.y * v.y + v.z * v.z + v.w * v.w;
#pragma unroll
    for (int m = 1; m < 64; m <<= 1) {
        s  += __shfl_xor(s, m, 64);
        s2 += __shfl_xor(s2, m, 64);
    }
    __shared__ float red[8];
    const int wv = t >> 6, ln = t & 63;
    if (ln == 0) { red[wv] = s; red[4 + wv] = s2; }
    __syncthreads();
    s  = red[0] + red[1] + red[2] + red[3];
    s2 = red[4] + red[5] + red[6] + red[7];
    const float mu  = s * (1.f / (float)D_);
    const float var = s2 * (1.f / (float)D_) - mu * mu;
    const float rs  = rsqrtf(var + 1e-5f);
    const float4 gv = ((const float4*)g)[t];
    const float4 bv = ((const float4*)be)[t];
    union { bf16 h[4]; short4 s4; } u;
    u.h[0] = __float2bfloat16((v.x - mu) * rs * gv.x + bv.x);
    u.h[1] = __float2bfloat16((v.y - mu) * rs * gv.y + bv.y);
    u.h[2] = __float2bfloat16((v.z - mu) * rs * gv.z + bv.z);
    u.h[3] = __float2bfloat16((v.w - mu) * rs * gv.w + bv.w);
    ((short4*)(out + row * D_))[t] = u.s4;
}

// ---------------------------------------------------------------- GEMM: C[M,N] = A[M,K] @ BT[N,K]^T
template<int HAS_BIAS, int RELU, int HAS_RES, int OUT_BF16>
__global__ __launch_bounds__(256, 2) void gemm_bt(
    const bf16* __restrict__ A, const bf16* __restrict__ BT,
    const float* __restrict__ bias, const float* __restrict__ res,
    void* __restrict__ Cout, int M, int N, int K)
{
    __shared__ bf16 As[128 * 32];
    __shared__ bf16 Bs[128 * 32];
    const int tid  = threadIdx.x;
    const int wave = tid >> 6;
    const int lane = tid & 63;
    const int nbn  = N >> 7;
    const int bm = blockIdx.x / nbn;
    const int bn = blockIdx.x % nbn;
    const int row0 = bm << 7, col0 = bn << 7;
    const int wm = wave & 1, wn = wave >> 1;

    const int srow = tid >> 2;
    const int scol = (tid & 3) << 3;
    const bf16* aSrc = A  + (long)(row0 + srow) * K + scol;
    const bf16* bSrc = BT + (long)(col0 + srow) * K + scol;
    bf16* aDst1 = As + wave * 512;
    bf16* aDst2 = As + 2048 + wave * 512;
    bf16* bDst1 = Bs + wave * 512;
    bf16* bDst2 = Bs + 2048 + wave * 512;

    f32x4_t acc[4][4] = {};

    const int fr = lane & 15;
    const int fk = (lane >> 4) << 3;

    for (int k0 = 0; k0 < K; k0 += 32) {
        gload_lds16(aSrc + k0, aDst1);
        gload_lds16(aSrc + k0 + (long)64 * K, aDst2);
        gload_lds16(bSrc + k0, bDst1);
        gload_lds16(bSrc + k0 + (long)64 * K, bDst2);
        __syncthreads();
        bf16x8_t a[4], b[4];
#pragma unroll
        for (int m = 0; m < 4; ++m)
            a[m] = ldsv8(As + (wm * 64 + m * 16 + fr) * 32 + fk);
#pragma unroll
        for (int n = 0; n < 4; ++n)
            b[n] = ldsv8(Bs + (wn * 64 + n * 16 + fr) * 32 + fk);
#pragma unroll
        for (int m = 0; m < 4; ++m)
#pragma unroll
            for (int n = 0; n < 4; ++n)
                acc[m][n] = __builtin_amdgcn_mfma_f32_16x16x32_bf16(a[m], b[n], acc[m][n], 0, 0, 0);
        __syncthreads();
    }

    const int orow = (lane >> 4) << 2;
#pragma unroll
    for (int m = 0; m < 4; ++m) {
        const int rbase = row0 + wm * 64 + m * 16 + orow;
#pragma unroll
        for (int n = 0; n < 4; ++n) {
            const int c = col0 + wn * 64 + n * 16 + fr;
            float bv = 0.f;
            if (HAS_BIAS) bv = bias[c];
#pragma unroll
            for (int r = 0; r < 4; ++r) {
                float v = acc[m][n][r] + bv;
                if (RELU) v = fmaxf(v, 0.f);
                if (HAS_RES) v += res[(long)(rbase + r) * N + c];
                if (OUT_BF16)
                    ((bf16*)Cout)[(long)(rbase + r) * N + c] = __float2bfloat16(v);
                else
                    ((float*)Cout)[(long)(rbase + r) * N + c] = v;
            }
        }
    }
}

// ---------------------------------------------------------------- flash attention (causal) v2
// Q,K: bf16 [B*T, D]; VT: bf16 [B*H*HS, T]; O: bf16 [B*T, D].
// grid: (T/64, B*H), 256 threads = 4 waves, wave w owns 16 q-rows.
// K/VT tiles double-buffered in LDS with XOR swizzle (col ^= (row&7)<<3, elements),
// staged via global_load_lds with PRE-SWIZZLED per-lane global source (rule #21).
__global__ __launch_bounds__(256, 4) void attn_flash(
    const bf16* __restrict__ Q, const bf16* __restrict__ Kg,
    const bf16* __restrict__ VT, bf16* __restrict__ O)
{
    __shared__ bf16 Ks[2][64 * 64];   // K tile [kr][hs], swizzled
    __shared__ bf16 Vs[2][64 * 64];   // V^T tile [hs][kr], swizzled
    __shared__ bf16 Ps[4][16 * 64];   // per-wave P [q][kr], swizzled

    const int tid = threadIdx.x;
    const int wave = tid >> 6, lane = tid & 63;
    const int fr = lane & 15, fk = (lane >> 4) << 3;
    const int frs = (fr & 7) << 3;           // read-side swizzle
    const int orow = (lane >> 4) << 2;

    const int qt = (int)gridDim.x - 1 - (int)blockIdx.x;  // heavy blocks first
    const int bh = blockIdx.y;
    const int b = bh >> 4, h = bh & 15;
    const long rowBase = (long)b * T_;
    const int colBase = h * HS_;

    // Q fragments: lane holds Q[q=fr][hs = fk..fk+7] per 32-slice
    const long qrow = rowBase + qt * 64 + wave * 16 + fr;
    bf16x8_t qf[2];
    qf[0] = *(const bf16x8_t*)(Q + qrow * D_ + colBase + fk);
    qf[1] = *(const bf16x8_t*)(Q + qrow * D_ + colBase + 32 + fk);

    f32x4_t o[4] = {};
    float mOld[4], lOld[4];
#pragma unroll
    for (int r = 0; r < 4; ++r) { mOld[r] = -1e30f; lOld[r] = 0.f; }

    // staging: thread t covers row svr (0..31), source chunk pre-swizzled so the
    // LINEAR wave write (base + lane*16B) lands the swizzled layout in LDS.
    const int svr = tid >> 3;
    const int svc = (((tid & 7) ^ (svr & 7)) << 3);
    const bf16* kSrc = Kg + (rowBase + svr) * D_ + colBase + svc;
    const bf16* vSrc = VT + ((long)bh * HS_ + svr) * T_ + svc;

    bf16* Pw = Ps[wave];

    // prologue: stage tile 0 into buffer 0
    {
        gload_lds16(kSrc, &Ks[0][wave * 512]);
        gload_lds16(kSrc + (long)32 * D_, &Ks[0][2048 + wave * 512]);
        gload_lds16(vSrc, &Vs[0][wave * 512]);
        gload_lds16(vSrc + (long)32 * T_, &Vs[0][2048 + wave * 512]);
    }

    for (int c = 0; c <= qt; ++c) {
        const int cur = c & 1;
        __syncthreads();   // drains vmcnt: buf[cur] ready; prev iter's reads done

        if (c < qt) {      // prefetch next tile into the other buffer
            const bf16* ks = kSrc + (long)(c + 1) * 64 * D_;
            const bf16* vs = vSrc + (c + 1) * 64;
            gload_lds16(ks, &Ks[cur ^ 1][wave * 512]);
            gload_lds16(ks + (long)32 * D_, &Ks[cur ^ 1][2048 + wave * 512]);
            gload_lds16(vs, &Vs[cur ^ 1][wave * 512]);
            gload_lds16(vs + (long)32 * T_, &Vs[cur ^ 1][2048 + wave * 512]);
        }

        // S = Q K^T  (S[q][kr], 16x64 per wave)
        const bf16* kb_ = Ks[cur];
        f32x4_t s[4] = {};
#pragma unroll
        for (int kk = 0; kk < 4; ++kk) {
            bf16x8_t kf0 = ldsv8(kb_ + (kk * 16 + fr) * 64 + (fk ^ frs));
            bf16x8_t kf1 = ldsv8(kb_ + (kk * 16 + fr) * 64 + ((32 + fk) ^ frs));
            s[kk] = __builtin_amdgcn_mfma_f32_16x16x32_bf16(qf[0], kf0, s[kk], 0, 0, 0);
            s[kk] = __builtin_amdgcn_mfma_f32_16x16x32_bf16(qf[1], kf1, s[kk], 0, 0, 0);
        }

        // scale (D^-0.5 = 1/32), causal mask, online softmax
        const int qrel = qt * 64 + wave * 16 + orow;
        float p[4][4];
#pragma unroll
        for (int r = 0; r < 4; ++r) {
            float rm = -1e30f;
#pragma unroll
            for (int kk = 0; kk < 4; ++kk) {
                float sv = s[kk][r] * 0.03125f;
                const int kabs = c * 64 + kk * 16 + fr;
                if (c == qt && kabs > qrel + r) sv = -1e30f;
                p[kk][r] = sv;
                rm = fmaxf(rm, sv);
            }
#pragma unroll
            for (int mm = 1; mm < 16; mm <<= 1)
                rm = fmaxf(rm, __shfl_xor(rm, mm, 64));
            const float mNew = fmaxf(mOld[r], rm);
            const float corr = __expf(mOld[r] - mNew);
            float rsum = 0.f;
#pragma unroll
            for (int kk = 0; kk < 4; ++kk) {
                const float pe = __expf(p[kk][r] - mNew);
                p[kk][r] = pe;
                rsum += pe;
            }
#pragma unroll
            for (int mm = 1; mm < 16; mm <<= 1)
                rsum += __shfl_xor(rsum, mm, 64);
            lOld[r] = lOld[r] * corr + rsum;
            mOld[r] = mNew;
#pragma unroll
            for (int n = 0; n < 4; ++n) o[n][r] *= corr;
        }

        // P -> per-wave LDS (swizzled; no barrier needed, same-wave producer/consumer)
#pragma unroll
        for (int kk = 0; kk < 4; ++kk)
#pragma unroll
            for (int r = 0; r < 4; ++r) {
                const int prow = orow + r;
                Pw[prow * 64 + ((kk * 16 + fr) ^ ((prow & 7) << 3))] = __float2bfloat16(p[kk][r]);
            }

        // O += P V   (B-operand = V^T rows = hs)
        const bf16* vb_ = Vs[cur];
#pragma unroll
        for (int ks = 0; ks < 2; ++ks) {
            bf16x8_t pa = ldsv8(Pw + fr * 64 + ((ks * 32 + fk) ^ frs));
#pragma unroll
            for (int n = 0; n < 4; ++n) {
                bf16x8_t vf = ldsv8(vb_ + (n * 16 + fr) * 64 + ((ks * 32 + fk) ^ frs));
                o[n] = __builtin_amdgcn_mfma_f32_16x16x32_bf16(pa, vf, o[n], 0, 0, 0);
            }
        }
    }

    // normalize + store
    const long orowg = rowBase + qt * 64 + wave * 16 + orow;
#pragma unroll
    for (int n = 0; n < 4; ++n) {
        const int cg = colBase + n * 16 + fr;
#pragma unroll
        for (int r = 0; r < 4; ++r)
            O[(orowg + r) * D_ + cg] = __float2bfloat16(o[n][r] / lOld[r]);
    }
}

// ---------------------------------------------------------------- launch
extern "C" void kernel_launch(void* const* d_in, const int* in_sizes, int n_in,
                              void* d_out, int out_size, void* d_ws, size_t ws_size,
                              hipStream_t stream)
{
    (void)in_sizes; (void)n_in; (void)out_size; (void)ws_size;
    const float* x   = (const float*)d_in[0];
    const float* wq  = (const float*)d_in[1];
    const float* wk  = (const float*)d_in[2];
    const float* wv  = (const float*)d_in[3];
    const float* wo  = (const float*)d_in[4];
    const float* bo  = (const float*)d_in[5];
    const float* w1  = (const float*)d_in[6];
    const float* b1  = (const float*)d_in[7];
    const float* w2  = (const float*)d_in[8];
    const float* b2  = (const float*)d_in[9];
    const float* g1  = (const float*)d_in[10];
    const float* be1 = (const float*)d_in[11];
    const float* g2  = (const float*)d_in[12];
    const float* be2 = (const float*)d_in[13];
    float* out = (float*)d_out;

    char* ws = (char*)d_ws;
    const size_t SLOT = (size_t)8192 * 1024 * 2;   // 16MB bf16 [8192,1024]
    // slot plan:
    //  slot0: xn -> attnb      slot1: qb -> xn2
    //  slot2: kb               slot3: vb
    //  slot4: vtb (V^T per-head, dead after attention)
    //  slot2..5 -> hidden (64MB, after attention)
    bf16* xn     = (bf16*)(ws);
    bf16* attnb  = (bf16*)(ws);
    bf16* qb     = (bf16*)(ws + SLOT);
    bf16* xn2    = (bf16*)(ws + SLOT);
    bf16* kb     = (bf16*)(ws + 2 * SLOT);
    bf16* vb     = (bf16*)(ws + 3 * SLOT);
    bf16* vtb    = (bf16*)(ws + 4 * SLOT);
    bf16* hidden = (bf16*)(ws + 2 * SLOT);
    float* x1    = (float*)(ws + 6 * SLOT);
    char* wpos   = ws + 6 * SLOT + (size_t)33554432;
    bf16* wqT = (bf16*)(wpos);
    bf16* wkT = (bf16*)(wpos + (size_t)2097152);
    bf16* wvT = (bf16*)(wpos + (size_t)2 * 2097152);
    bf16* woT = (bf16*)(wpos + (size_t)3 * 2097152);
    bf16* w1T = (bf16*)(wpos + (size_t)4 * 2097152);
    bf16* w2T = (bf16*)(wpos + (size_t)4 * 2097152 + 8388608);

    transpose_cvt<<<dim3(1024), 256, 0, stream>>>(wq, wqT, 1024, 1024);
    transpose_cvt<<<dim3(1024), 256, 0, stream>>>(wk, wkT, 1024, 1024);
    transpose_cvt<<<dim3(1024), 256, 0, stream>>>(wv, wvT, 1024, 1024);
    transpose_cvt<<<dim3(1024), 256, 0, stream>>>(wo, woT, 1024, 1024);
    transpose_cvt<<<dim3(4096), 256, 0, stream>>>(w1, w1T, 1024, 4096);
    transpose_cvt<<<dim3(4096), 256, 0, stream>>>(w2, w2T, 4096, 1024);

    ln_k<<<8192, 256, 0, stream>>>(x, g1, be1, xn);

    gemm_bt<0, 0, 0, 1><<<512, 256, 0, stream>>>(xn, wqT, nullptr, nullptr, qb, 8192, 1024, 1024);
    gemm_bt<0, 0, 0, 1><<<512, 256, 0, stream>>>(xn, wkT, nullptr, nullptr, kb, 8192, 1024, 1024);
    gemm_bt<0, 0, 0, 1><<<512, 256, 0, stream>>>(xn, wvT, nullptr, nullptr, vb, 8192, 1024, 1024);

    // V -> V^T per head (16MB+16MB traffic, ~6us)
    vhead_transpose<<<8192, 256, 0, stream>>>(vb, vtb);

    attn_flash<<<dim3(32, 64), 256, 0, stream>>>(qb, kb, vtb, attnb);

    gemm_bt<1, 0, 1, 0><<<512, 256, 0, stream>>>(attnb, woT, bo, x, x1, 8192, 1024, 1024);

    ln_k<<<8192, 256, 0, stream>>>(x1, g2, be2, xn2);

    gemm_bt<1, 1, 0, 1><<<2048, 256, 0, stream>>>(xn2, w1T, b1, nullptr, hidden, 8192, 4096, 1024);

    gemm_bt<1, 0, 1, 0><<<512, 256, 0, stream>>>(hidden, w2T, b2, x1, out, 8192, 1024, 4096);
}

// Round 3
// 597.608 us; speedup vs baseline: 1.3863x; 1.1081x over previous
//
#include <hip/hip_runtime.h>
#include <hip/hip_bf16.h>
#include <stdint.h>

typedef __hip_bfloat16 bf16;
typedef __attribute__((ext_vector_type(8))) short bf16x8_t;
typedef __attribute__((ext_vector_type(4))) float f32x4_t;
typedef __attribute__((ext_vector_type(16))) float f32x16_t;
typedef __attribute__((ext_vector_type(2))) unsigned int u32x2_t;

#define B_ 4
#define T_ 2048
#define D_ 1024
#define H_ 16
#define HS_ 64

// ---------------------------------------------------------------- helpers
__device__ __forceinline__ void gload_lds16(const void* g, void* l) {
    __builtin_amdgcn_global_load_lds(
        (const __attribute__((address_space(1))) unsigned int*)g,
        (__attribute__((address_space(3))) unsigned int*)l, 16, 0, 0);
}

__device__ __forceinline__ bf16x8_t ldsv8(const bf16* p) {
    return *(const bf16x8_t*)p;
}

__device__ __forceinline__ unsigned pack2(float a, float b) {
    union { bf16 h[2]; unsigned u; } t;
    t.h[0] = __float2bfloat16(a);
    t.h[1] = __float2bfloat16(b);
    return t.u;
}

// ---------------------------------------------------------------- weight transpose + fp32->bf16
// W[K,N] fp32 -> WT[N,K] bf16
__global__ __launch_bounds__(256) void transpose_cvt(
    const float* __restrict__ W, bf16* __restrict__ WT, int K, int N)
{
    __shared__ float tile[32][33];
    const int nbx = N >> 5;
    const int bx = blockIdx.x % nbx;   // n-tile
    const int by = blockIdx.x / nbx;   // k-tile
    const int n0 = bx << 5, k0 = by << 5;
    const int tx = threadIdx.x & 31, ty = threadIdx.x >> 5;  // ty 0..7
#pragma unroll
    for (int i = 0; i < 32; i += 8)
        tile[ty + i][tx] = W[(long)(k0 + ty + i) * N + n0 + tx];
    __syncthreads();
#pragma unroll
    for (int i = 0; i < 32; i += 8)
        WT[(long)(n0 + ty + i) * K + k0 + tx] = __float2bfloat16(tile[tx][ty + i]);
}

// ---------------------------------------------------------------- per-head V transpose (bf16)
// V [B*T, D] -> VT [B*H*HS, T]  (row = bh*64+hs, col = t)
__global__ __launch_bounds__(256) void vhead_transpose(
    const bf16* __restrict__ V, bf16* __restrict__ VT)
{
    __shared__ bf16 tile[32][33];
    int idx = blockIdx.x;
    const int tt  = idx & 63;   idx >>= 6;   // t-tile (T/32 = 64)
    const int hst = idx & 1;    idx >>= 1;   // hs-tile (HS/32 = 2)
    const int bh  = idx;                     // 0..63
    const int b = bh >> 4, h = bh & 15;
    const int tx = threadIdx.x & 31, ty = threadIdx.x >> 5;
    const long vrow = (long)b * T_ + tt * 32;
    const int  vcol = h * HS_ + hst * 32;
#pragma unroll
    for (int i = 0; i < 32; i += 8)
        tile[ty + i][tx] = V[(vrow + ty + i) * D_ + vcol + tx];
    __syncthreads();
    const long orow = (long)bh * HS_ + hst * 32;
#pragma unroll
    for (int i = 0; i < 32; i += 8)
        VT[(orow + ty + i) * T_ + tt * 32 + tx] = tile[tx][ty + i];
}

// ---------------------------------------------------------------- LayerNorm (fp32 in -> bf16 out)
__global__ __launch_bounds__(256) void ln_k(
    const float* __restrict__ x, const float* __restrict__ g,
    const float* __restrict__ be, bf16* __restrict__ out)
{
    const long row = blockIdx.x;
    const int t = threadIdx.x;
    const float4 v = ((const float4*)(x + row * D_))[t];
    float s  = v.x + v.y + v.z + v.w;
    float s2 = v.x * v.x + v.y * v.y + v.z * v.z + v.w * v.w;
#pragma unroll
    for (int m = 1; m < 64; m <<= 1) {
        s  += __shfl_xor(s, m, 64);
        s2 += __shfl_xor(s2, m, 64);
    }
    __shared__ float red[8];
    const int wv = t >> 6, ln = t & 63;
    if (ln == 0) { red[wv] = s; red[4 + wv] = s2; }
    __syncthreads();
    s  = red[0] + red[1] + red[2] + red[3];
    s2 = red[4] + red[5] + red[6] + red[7];
    const float mu  = s * (1.f / (float)D_);
    const float var = s2 * (1.f / (float)D_) - mu * mu;
    const float rs  = rsqrtf(var + 1e-5f);
    const float4 gv = ((const float4*)g)[t];
    const float4 bv = ((const float4*)be)[t];
    union { bf16 h[4]; short4 s4; } u;
    u.h[0] = __float2bfloat16((v.x - mu) * rs * gv.x + bv.x);
    u.h[1] = __float2bfloat16((v.y - mu) * rs * gv.y + bv.y);
    u.h[2] = __float2bfloat16((v.z - mu) * rs * gv.z + bv.z);
    u.h[3] = __float2bfloat16((v.w - mu) * rs * gv.w + bv.w);
    ((short4*)(out + row * D_))[t] = u.s4;
}

// ---------------------------------------------------------------- GEMM: C[M,N] = A[M,K] @ BT[N,K]^T
template<int HAS_BIAS, int RELU, int HAS_RES, int OUT_BF16>
__global__ __launch_bounds__(256, 2) void gemm_bt(
    const bf16* __restrict__ A, const bf16* __restrict__ BT,
    const float* __restrict__ bias, const float* __restrict__ res,
    void* __restrict__ Cout, int M, int N, int K)
{
    __shared__ bf16 As[128 * 32];
    __shared__ bf16 Bs[128 * 32];
    const int tid  = threadIdx.x;
    const int wave = tid >> 6;
    const int lane = tid & 63;
    const int nbn  = N >> 7;
    const int bm = blockIdx.x / nbn;
    const int bn = blockIdx.x % nbn;
    const int row0 = bm << 7, col0 = bn << 7;
    const int wm = wave & 1, wn = wave >> 1;

    const int srow = tid >> 2;
    const int scol = (tid & 3) << 3;
    const bf16* aSrc = A  + (long)(row0 + srow) * K + scol;
    const bf16* bSrc = BT + (long)(col0 + srow) * K + scol;
    bf16* aDst1 = As + wave * 512;
    bf16* aDst2 = As + 2048 + wave * 512;
    bf16* bDst1 = Bs + wave * 512;
    bf16* bDst2 = Bs + 2048 + wave * 512;

    f32x4_t acc[4][4] = {};

    const int fr = lane & 15;
    const int fk = (lane >> 4) << 3;

    for (int k0 = 0; k0 < K; k0 += 32) {
        gload_lds16(aSrc + k0, aDst1);
        gload_lds16(aSrc + k0 + (long)64 * K, aDst2);
        gload_lds16(bSrc + k0, bDst1);
        gload_lds16(bSrc + k0 + (long)64 * K, bDst2);
        __syncthreads();
        bf16x8_t a[4], b[4];
#pragma unroll
        for (int m = 0; m < 4; ++m)
            a[m] = ldsv8(As + (wm * 64 + m * 16 + fr) * 32 + fk);
#pragma unroll
        for (int n = 0; n < 4; ++n)
            b[n] = ldsv8(Bs + (wn * 64 + n * 16 + fr) * 32 + fk);
#pragma unroll
        for (int m = 0; m < 4; ++m)
#pragma unroll
            for (int n = 0; n < 4; ++n)
                acc[m][n] = __builtin_amdgcn_mfma_f32_16x16x32_bf16(a[m], b[n], acc[m][n], 0, 0, 0);
        __syncthreads();
    }

    const int orow = (lane >> 4) << 2;
#pragma unroll
    for (int m = 0; m < 4; ++m) {
        const int rbase = row0 + wm * 64 + m * 16 + orow;
#pragma unroll
        for (int n = 0; n < 4; ++n) {
            const int c = col0 + wn * 64 + n * 16 + fr;
            float bv = 0.f;
            if (HAS_BIAS) bv = bias[c];
#pragma unroll
            for (int r = 0; r < 4; ++r) {
                float v = acc[m][n][r] + bv;
                if (RELU) v = fmaxf(v, 0.f);
                if (HAS_RES) v += res[(long)(rbase + r) * N + c];
                if (OUT_BF16)
                    ((bf16*)Cout)[(long)(rbase + r) * N + c] = __float2bfloat16(v);
                else
                    ((float*)Cout)[(long)(rbase + r) * N + c] = v;
            }
        }
    }
}

// ---------------------------------------------------------------- flash attention (causal) v3
// Swapped-operand 32x32x16 structure (m214-style): S^T = mfma(K,Q) puts col=q=lane&31
// -> softmax fully lane-local/in-register; O kept transposed (O^T = mfma(V^T, P)).
// Q,K: bf16 [B*T, D]; VT: bf16 [B*H*HS, T]; O: bf16 [B*T, D].
// grid: (T/256, B*H), 512 threads = 8 waves, wave w owns 32 q-rows.
__global__ __launch_bounds__(512, 4) void attn_flash(
    const bf16* __restrict__ Q, const bf16* __restrict__ Kg,
    const bf16* __restrict__ VT, bf16* __restrict__ O)
{
    __shared__ bf16 Ks[2][64 * 64];   // K tile [kv][hs], XOR-swizzled
    __shared__ bf16 Vs[2][64 * 64];   // V^T tile [hs][kv], XOR-swizzled

    const int tid = threadIdx.x;
    const int w   = tid >> 6;          // wave 0..7
    const int ln  = tid & 63;
    const int l31 = ln & 31;
    const int hi  = ln >> 5;
    const int hi8 = hi << 3;

    const int qb = 7 - (int)blockIdx.x;   // heavy q-blocks first
    const int bh = blockIdx.y;
    const long rowBase = (long)(bh >> 4) * T_;
    const int colBase = (bh & 15) * HS_;

    const int qwbase = qb * 256 + w * 32;   // warp's first q row
    const int qabs   = qwbase + l31;        // this lane's q row
    const int ctb  = qb * 4 + 3;            // last kv tile staged by block
    const int ct_w = qb * 4 + (w >> 1);     // warp's last compute tile

    // Q fragments: lane holds Q[q=l31][hs = 16s + hi8 + j]  (B-operand layout)
    const bf16* qp = Q + (rowBase + qabs) * D_ + colBase + hi8;
    bf16x8_t qf[4];
#pragma unroll
    for (int s = 0; s < 4; ++s) qf[s] = *(const bf16x8_t*)(qp + 16 * s);

    f32x16_t oA = {}, oB = {};   // O^T accum: col=q=l31, row hs = (r&3)+8*(r>>2)+4*hi (+32 for oB)
    float mOld = -1e30f, lSum = 0.f;
    const float kE = 0.0450842200278f;   // (1/32) * log2(e)

    // staging: thread t -> row t>>3, chunk pre-swizzled so linear LDS write lands swizzled
    const int srow = tid >> 3;                              // 0..63
    const int schunk = (((tid & 7) ^ (srow & 7)) << 3);     // elements
    const bf16* kSrc = Kg + (rowBase + srow) * D_ + colBase + schunk;
    const bf16* vSrc = VT + ((long)bh * HS_ + srow) * T_ + schunk;

    // prologue: stage tile 0 into buffer 0
    gload_lds16(kSrc, &Ks[0][w * 512]);
    gload_lds16(vSrc, &Vs[0][w * 512]);

    for (int c = 0; c <= ctb; ++c) {
        const int cur = c & 1;
        __syncthreads();   // buf[cur] staged (barrier drains vmcnt), prev reads done

        if (c < ctb) {     // prefetch next tile
            gload_lds16(kSrc + (long)(c + 1) * 64 * D_, &Ks[cur ^ 1][w * 512]);
            gload_lds16(vSrc + (c + 1) * 64, &Vs[cur ^ 1][w * 512]);
        }
        if (c > ct_w) continue;   // this warp done computing; keep hitting barriers

        const bf16* K_ = Ks[cur];
        const bf16* V_ = Vs[cur];
        const int swzk = (l31 & 7) << 3;

        for (int st = 0; st < 2; ++st) {
            if (c * 64 + st * 32 > qwbase + 31) break;   // subtile fully above diagonal

            // ---- S^T[kv][q] = K Q^T : 4 hs-slices of K=16
            f32x16_t sa = {};
            const int krow = st * 32 + l31;
#pragma unroll
            for (int s = 0; s < 4; ++s) {
                bf16x8_t kf = ldsv8(K_ + krow * 64 + ((16 * s + hi8) ^ swzk));
                sa = __builtin_amdgcn_mfma_f32_32x32x16_bf16(kf, qf[s], sa, 0, 0, 0);
            }

            // ---- causal mask (diagonal tile only); kv = st*32 + (r&3)+8*(r>>2)+4*hi
            if (c == ct_w) {
                const int kb0 = c * 64 + st * 32 + 4 * hi;
#pragma unroll
                for (int r = 0; r < 16; ++r) {
                    const int kabs = kb0 + (r & 3) + 8 * (r >> 2);
                    if (kabs > qabs) sa[r] = -1e30f;
                }
            }

            // ---- online softmax (lane-local row q)
            float rm = sa[0];
#pragma unroll
            for (int r = 1; r < 16; ++r) rm = fmaxf(rm, sa[r]);
            {
                u32x2_t rr = __builtin_amdgcn_permlane32_swap(
                    __float_as_uint(rm), __float_as_uint(rm), false, false);
                rm = fmaxf(__uint_as_float(rr.x), __uint_as_float(rr.y));
            }
            const float mN = fmaxf(mOld, rm);
            const float corr = exp2f((mOld - mN) * kE);
            mOld = mN;
            const float nmk = -mN * kE;
#pragma unroll
            for (int r = 0; r < 16; ++r) sa[r] = exp2f(fmaf(sa[r], kE, nmk));
            float rs = sa[0];
#pragma unroll
            for (int r = 1; r < 16; ++r) rs += sa[r];
            {
                u32x2_t rr = __builtin_amdgcn_permlane32_swap(
                    __float_as_uint(rs), __float_as_uint(rs), false, false);
                rs = __uint_as_float(rr.x) + __uint_as_float(rr.y);
            }
            lSum = lSum * corr + rs;
#pragma unroll
            for (int r = 0; r < 16; ++r) { oA[r] *= corr; oB[r] *= corr; }

            // ---- pack P to bf16 words + permlane32_swap redistribution (T12)
            unsigned pk_[8];
#pragma unroll
            for (int i = 0; i < 8; ++i) pk_[i] = pack2(sa[2 * i], sa[2 * i + 1]);
            union { unsigned u[4]; bf16x8_t v; } W0, W1;
            {
                u32x2_t ra = __builtin_amdgcn_permlane32_swap(pk_[0], pk_[2], false, false);
                u32x2_t rb = __builtin_amdgcn_permlane32_swap(pk_[1], pk_[3], false, false);
                W0.u[0] = ra.x; W0.u[1] = rb.x; W0.u[2] = ra.y; W0.u[3] = rb.y;
                u32x2_t rc = __builtin_amdgcn_permlane32_swap(pk_[4], pk_[6], false, false);
                u32x2_t rd = __builtin_amdgcn_permlane32_swap(pk_[5], pk_[7], false, false);
                W1.u[0] = rc.x; W1.u[1] = rd.x; W1.u[2] = rc.y; W1.u[3] = rd.y;
            }

            // ---- O^T += V^T P : kv-slices (st*2+m), hs halves
#pragma unroll
            for (int m = 0; m < 2; ++m) {
                const int kcol = 16 * (st * 2 + m) + hi8;
                bf16x8_t vf0 = ldsv8(V_ + l31 * 64 + (kcol ^ swzk));
                oA = __builtin_amdgcn_mfma_f32_32x32x16_bf16(vf0, m ? W1.v : W0.v, oA, 0, 0, 0);
                const int vr1 = 32 + l31;
                bf16x8_t vf1 = ldsv8(V_ + vr1 * 64 + (kcol ^ swzk));
                oB = __builtin_amdgcn_mfma_f32_32x32x16_bf16(vf1, m ? W1.v : W0.v, oB, 0, 0, 0);
            }
        }
    }

    // ---- normalize + store: lane owns q=qabs; reg r -> hs = (r&3)+8*(r>>2)+4*hi
    const float inv = 1.f / lSum;
    bf16* Op = O + (rowBase + qabs) * D_ + colBase;
#pragma unroll
    for (int g = 0; g < 4; ++g) {
        u32x2_t sA, sB;
        sA.x = pack2(oA[4 * g + 0] * inv, oA[4 * g + 1] * inv);
        sA.y = pack2(oA[4 * g + 2] * inv, oA[4 * g + 3] * inv);
        sB.x = pack2(oB[4 * g + 0] * inv, oB[4 * g + 1] * inv);
        sB.y = pack2(oB[4 * g + 2] * inv, oB[4 * g + 3] * inv);
        *(u32x2_t*)(Op + 8 * g + 4 * hi)      = sA;
        *(u32x2_t*)(Op + 32 + 8 * g + 4 * hi) = sB;
    }
}

// ---------------------------------------------------------------- launch
extern "C" void kernel_launch(void* const* d_in, const int* in_sizes, int n_in,
                              void* d_out, int out_size, void* d_ws, size_t ws_size,
                              hipStream_t stream)
{
    (void)in_sizes; (void)n_in; (void)out_size; (void)ws_size;
    const float* x   = (const float*)d_in[0];
    const float* wq  = (const float*)d_in[1];
    const float* wk  = (const float*)d_in[2];
    const float* wv  = (const float*)d_in[3];
    const float* wo  = (const float*)d_in[4];
    const float* bo  = (const float*)d_in[5];
    const float* w1  = (const float*)d_in[6];
    const float* b1  = (const float*)d_in[7];
    const float* w2  = (const float*)d_in[8];
    const float* b2  = (const float*)d_in[9];
    const float* g1  = (const float*)d_in[10];
    const float* be1 = (const float*)d_in[11];
    const float* g2  = (const float*)d_in[12];
    const float* be2 = (const float*)d_in[13];
    float* out = (float*)d_out;

    char* ws = (char*)d_ws;
    const size_t SLOT = (size_t)8192 * 1024 * 2;   // 16MB bf16 [8192,1024]
    bf16* xn     = (bf16*)(ws);
    bf16* attnb  = (bf16*)(ws);
    bf16* qb     = (bf16*)(ws + SLOT);
    bf16* xn2    = (bf16*)(ws + SLOT);
    bf16* kb     = (bf16*)(ws + 2 * SLOT);
    bf16* vb     = (bf16*)(ws + 3 * SLOT);
    bf16* vtb    = (bf16*)(ws + 4 * SLOT);
    bf16* hidden = (bf16*)(ws + 2 * SLOT);
    float* x1    = (float*)(ws + 6 * SLOT);
    char* wpos   = ws + 6 * SLOT + (size_t)33554432;
    bf16* wqT = (bf16*)(wpos);
    bf16* wkT = (bf16*)(wpos + (size_t)2097152);
    bf16* wvT = (bf16*)(wpos + (size_t)2 * 2097152);
    bf16* woT = (bf16*)(wpos + (size_t)3 * 2097152);
    bf16* w1T = (bf16*)(wpos + (size_t)4 * 2097152);
    bf16* w2T = (bf16*)(wpos + (size_t)4 * 2097152 + 8388608);

    transpose_cvt<<<dim3(1024), 256, 0, stream>>>(wq, wqT, 1024, 1024);
    transpose_cvt<<<dim3(1024), 256, 0, stream>>>(wk, wkT, 1024, 1024);
    transpose_cvt<<<dim3(1024), 256, 0, stream>>>(wv, wvT, 1024, 1024);
    transpose_cvt<<<dim3(1024), 256, 0, stream>>>(wo, woT, 1024, 1024);
    transpose_cvt<<<dim3(4096), 256, 0, stream>>>(w1, w1T, 1024, 4096);
    transpose_cvt<<<dim3(4096), 256, 0, stream>>>(w2, w2T, 4096, 1024);

    ln_k<<<8192, 256, 0, stream>>>(x, g1, be1, xn);

    gemm_bt<0, 0, 0, 1><<<512, 256, 0, stream>>>(xn, wqT, nullptr, nullptr, qb, 8192, 1024, 1024);
    gemm_bt<0, 0, 0, 1><<<512, 256, 0, stream>>>(xn, wkT, nullptr, nullptr, kb, 8192, 1024, 1024);
    gemm_bt<0, 0, 0, 1><<<512, 256, 0, stream>>>(xn, wvT, nullptr, nullptr, vb, 8192, 1024, 1024);

    vhead_transpose<<<8192, 256, 0, stream>>>(vb, vtb);

    attn_flash<<<dim3(8, 64), 512, 0, stream>>>(qb, kb, vtb, attnb);

    gemm_bt<1, 0, 1, 0><<<512, 256, 0, stream>>>(attnb, woT, bo, x, x1, 8192, 1024, 1024);

    ln_k<<<8192, 256, 0, stream>>>(x1, g2, be2, xn2);

    gemm_bt<1, 1, 0, 1><<<2048, 256, 0, stream>>>(xn2, w1T, b1, nullptr, hidden, 8192, 4096, 1024);

    gemm_bt<1, 0, 1, 0><<<512, 256, 0, stream>>>(hidden, w2T, b2, x1, out, 8192, 1024, 4096);
}

// Round 4
// 560.952 us; speedup vs baseline: 1.4768x; 1.0653x over previous
//
#include <hip/hip_runtime.h>
#include <hip/hip_bf16.h>
#include <stdint.h>

typedef __hip_bfloat16 bf16;
typedef __attribute__((ext_vector_type(8))) short bf16x8_t;
typedef __attribute__((ext_vector_type(4))) float f32x4_t;
typedef __attribute__((ext_vector_type(16))) float f32x16_t;
typedef __attribute__((ext_vector_type(2))) unsigned int u32x2_t;

#define B_ 4
#define T_ 2048
#define D_ 1024
#define H_ 16
#define HS_ 64
#define QKV_LD 3072

// ---------------------------------------------------------------- helpers
__device__ __forceinline__ void gload_lds16(const void* g, void* l) {
    __builtin_amdgcn_global_load_lds(
        (const __attribute__((address_space(1))) unsigned int*)g,
        (__attribute__((address_space(3))) unsigned int*)l, 16, 0, 0);
}

__device__ __forceinline__ bf16x8_t ldsv8(const bf16* p) {
    return *(const bf16x8_t*)p;
}

__device__ __forceinline__ unsigned pack2(float a, float b) {
    union { bf16 h[2]; unsigned u; } t;
    t.h[0] = __float2bfloat16(a);
    t.h[1] = __float2bfloat16(b);
    return t.u;
}

// ---------------------------------------------------------------- weight transpose + fp32->bf16
// W[K,N] fp32 -> WT[N,K] bf16
__global__ __launch_bounds__(256) void transpose_cvt(
    const float* __restrict__ W, bf16* __restrict__ WT, int K, int N)
{
    __shared__ float tile[32][33];
    const int nbx = N >> 5;
    const int bx = blockIdx.x % nbx;   // n-tile
    const int by = blockIdx.x / nbx;   // k-tile
    const int n0 = bx << 5, k0 = by << 5;
    const int tx = threadIdx.x & 31, ty = threadIdx.x >> 5;  // ty 0..7
#pragma unroll
    for (int i = 0; i < 32; i += 8)
        tile[ty + i][tx] = W[(long)(k0 + ty + i) * N + n0 + tx];
    __syncthreads();
#pragma unroll
    for (int i = 0; i < 32; i += 8)
        WT[(long)(n0 + ty + i) * K + k0 + tx] = __float2bfloat16(tile[tx][ty + i]);
}

// ---------------------------------------------------------------- per-head V transpose (bf16)
// QKV [B*T, 3072] (V at cols 2048..3071) -> VT [B*H*HS, T]  (row = bh*64+hs, col = t)
__global__ __launch_bounds__(256) void vhead_transpose(
    const bf16* __restrict__ QKV, bf16* __restrict__ VT)
{
    __shared__ bf16 tile[32][33];
    int idx = blockIdx.x;
    const int tt  = idx & 63;   idx >>= 6;   // t-tile (T/32 = 64)
    const int hst = idx & 1;    idx >>= 1;   // hs-tile (HS/32 = 2)
    const int bh  = idx;                     // 0..63
    const int b = bh >> 4, h = bh & 15;
    const int tx = threadIdx.x & 31, ty = threadIdx.x >> 5;
    const long vrow = (long)b * T_ + tt * 32;
    const int  vcol = 2048 + h * HS_ + hst * 32;
#pragma unroll
    for (int i = 0; i < 32; i += 8)
        tile[ty + i][tx] = QKV[(vrow + ty + i) * QKV_LD + vcol + tx];
    __syncthreads();
    const long orow = (long)bh * HS_ + hst * 32;
#pragma unroll
    for (int i = 0; i < 32; i += 8)
        VT[(orow + ty + i) * T_ + tt * 32 + tx] = tile[tx][ty + i];
}

// ---------------------------------------------------------------- LayerNorm (fp32 in -> bf16 out)
__global__ __launch_bounds__(256) void ln_k(
    const float* __restrict__ x, const float* __restrict__ g,
    const float* __restrict__ be, bf16* __restrict__ out)
{
    const long row = blockIdx.x;
    const int t = threadIdx.x;
    const float4 v = ((const float4*)(x + row * D_))[t];
    float s  = v.x + v.y + v.z + v.w;
    float s2 = v.x * v.x + v.y * v.y + v.z * v.z + v.w * v.w;
#pragma unroll
    for (int m = 1; m < 64; m <<= 1) {
        s  += __shfl_xor(s, m, 64);
        s2 += __shfl_xor(s2, m, 64);
    }
    __shared__ float red[8];
    const int wv = t >> 6, ln = t & 63;
    if (ln == 0) { red[wv] = s; red[4 + wv] = s2; }
    __syncthreads();
    s  = red[0] + red[1] + red[2] + red[3];
    s2 = red[4] + red[5] + red[6] + red[7];
    const float mu  = s * (1.f / (float)D_);
    const float var = s2 * (1.f / (float)D_) - mu * mu;
    const float rs  = rsqrtf(var + 1e-5f);
    const float4 gv = ((const float4*)g)[t];
    const float4 bv = ((const float4*)be)[t];
    union { bf16 h[4]; short4 s4; } u;
    u.h[0] = __float2bfloat16((v.x - mu) * rs * gv.x + bv.x);
    u.h[1] = __float2bfloat16((v.y - mu) * rs * gv.y + bv.y);
    u.h[2] = __float2bfloat16((v.z - mu) * rs * gv.z + bv.z);
    u.h[3] = __float2bfloat16((v.w - mu) * rs * gv.w + bv.w);
    ((short4*)(out + row * D_))[t] = u.s4;
}

// ---------------------------------------------------------------- GEMM: C[M,N] = A[M,K] @ BT[N,K]^T
// T1 XCD swizzle: grid must be a multiple of 8 (all our launches are).
template<int HAS_BIAS, int RELU, int HAS_RES, int OUT_BF16>
__global__ __launch_bounds__(256, 2) void gemm_bt(
    const bf16* __restrict__ A, const bf16* __restrict__ BT,
    const float* __restrict__ bias, const float* __restrict__ res,
    void* __restrict__ Cout, int M, int N, int K)
{
    __shared__ bf16 As[128 * 32];
    __shared__ bf16 Bs[128 * 32];
    const int tid  = threadIdx.x;
    const int wave = tid >> 6;
    const int lane = tid & 63;
    const int nbn  = N >> 7;
    const int cpx  = gridDim.x >> 3;                       // blocks per XCD
    const int bid  = (blockIdx.x & 7) * cpx + (blockIdx.x >> 3);
    const int bm = bid / nbn;
    const int bn = bid % nbn;
    const int row0 = bm << 7, col0 = bn << 7;
    const int wm = wave & 1, wn = wave >> 1;

    const int srow = tid >> 2;
    const int scol = (tid & 3) << 3;
    const bf16* aSrc = A  + (long)(row0 + srow) * K + scol;
    const bf16* bSrc = BT + (long)(col0 + srow) * K + scol;
    bf16* aDst1 = As + wave * 512;
    bf16* aDst2 = As + 2048 + wave * 512;
    bf16* bDst1 = Bs + wave * 512;
    bf16* bDst2 = Bs + 2048 + wave * 512;

    f32x4_t acc[4][4] = {};

    const int fr = lane & 15;
    const int fk = (lane >> 4) << 3;

    for (int k0 = 0; k0 < K; k0 += 32) {
        gload_lds16(aSrc + k0, aDst1);
        gload_lds16(aSrc + k0 + (long)64 * K, aDst2);
        gload_lds16(bSrc + k0, bDst1);
        gload_lds16(bSrc + k0 + (long)64 * K, bDst2);
        __syncthreads();
        bf16x8_t a[4], b[4];
#pragma unroll
        for (int m = 0; m < 4; ++m)
            a[m] = ldsv8(As + (wm * 64 + m * 16 + fr) * 32 + fk);
#pragma unroll
        for (int n = 0; n < 4; ++n)
            b[n] = ldsv8(Bs + (wn * 64 + n * 16 + fr) * 32 + fk);
#pragma unroll
        for (int m = 0; m < 4; ++m)
#pragma unroll
            for (int n = 0; n < 4; ++n)
                acc[m][n] = __builtin_amdgcn_mfma_f32_16x16x32_bf16(a[m], b[n], acc[m][n], 0, 0, 0);
        __syncthreads();
    }

    const int orow = (lane >> 4) << 2;
#pragma unroll
    for (int m = 0; m < 4; ++m) {
        const int rbase = row0 + wm * 64 + m * 16 + orow;
#pragma unroll
        for (int n = 0; n < 4; ++n) {
            const int c = col0 + wn * 64 + n * 16 + fr;
            float bv = 0.f;
            if (HAS_BIAS) bv = bias[c];
#pragma unroll
            for (int r = 0; r < 4; ++r) {
                float v = acc[m][n][r] + bv;
                if (RELU) v = fmaxf(v, 0.f);
                if (HAS_RES) v += res[(long)(rbase + r) * N + c];
                if (OUT_BF16)
                    ((bf16*)Cout)[(long)(rbase + r) * N + c] = __float2bfloat16(v);
                else
                    ((float*)Cout)[(long)(rbase + r) * N + c] = v;
            }
        }
    }
}

// ---------------------------------------------------------------- flash attention (causal) v4
// Swapped-operand 32x32x16: S^T = mfma(K,Q) -> col=q=lane&31, softmax lane-local.
// v4: ONE softmax pass per 64-kv tile (both 32-kv subtiles), T13 defer-max,
// gated causal mask. Q,K read from interleaved QKV [B*T,3072]; V^T [B*H*64,T].
__global__ __launch_bounds__(512, 2) void attn_flash(
    const bf16* __restrict__ QKV, const bf16* __restrict__ VT,
    bf16* __restrict__ O)
{
    __shared__ bf16 Ks[2][64 * 64];   // K tile [kv][hs], XOR-swizzled
    __shared__ bf16 Vs[2][64 * 64];   // V^T tile [hs][kv], XOR-swizzled

    const int tid = threadIdx.x;
    const int w   = tid >> 6;          // wave 0..7
    const int ln  = tid & 63;
    const int l31 = ln & 31;
    const int hi  = ln >> 5;
    const int hi8 = hi << 3;

    const int qb = 7 - (int)blockIdx.x;   // heavy q-blocks first (per bh)
    const int bh = blockIdx.y;
    const long rowBase = (long)(bh >> 4) * T_;
    const int colBase = (bh & 15) * HS_;

    const int qwbase = qb * 256 + w * 32;   // wave's first q row
    const int qabs   = qwbase + l31;        // this lane's q row
    const int ctb  = qb * 4 + 3;            // last kv tile staged by block
    const int ct_w = qb * 4 + (w >> 1);     // wave's diagonal kv tile

    // Q fragments (B-operand): lane holds Q[q=l31][hs = 16s + hi8 + j]
    const bf16* qp = QKV + (rowBase + qabs) * QKV_LD + colBase + hi8;
    bf16x8_t qf[4];
#pragma unroll
    for (int s = 0; s < 4; ++s) qf[s] = *(const bf16x8_t*)(qp + 16 * s);

    f32x16_t oA = {}, oB = {};   // O^T accum: col=q=l31, row hs=(r&3)+8*(r>>2)+4*hi (+32 for oB)
    float mOld = -1e30f, lSum = 0.f;
    const float kE  = 0.0450842200278f;   // (1/32) * log2(e)
    const float THR = 256.0f;             // defer-max threshold (raw S units, = e^8 bound)

    // staging: thread t -> row t>>3, chunk pre-swizzled so linear LDS write lands swizzled
    const int srow = tid >> 3;                              // 0..63
    const int schunk = (((tid & 7) ^ (srow & 7)) << 3);     // elements
    const bf16* kSrc = QKV + (rowBase + srow) * QKV_LD + 1024 + colBase + schunk;
    const bf16* vSrc = VT + ((long)bh * HS_ + srow) * T_ + schunk;

    // prologue: stage tile 0 into buffer 0
    gload_lds16(kSrc, &Ks[0][w * 512]);
    gload_lds16(vSrc, &Vs[0][w * 512]);

    const int swzk = (l31 & 7) << 3;

    for (int c = 0; c <= ctb; ++c) {
        const int cur = c & 1;
        __syncthreads();   // buf[cur] staged (barrier drains vmcnt), prev reads done

        if (c < ctb) {     // prefetch next tile
            gload_lds16(kSrc + (long)(c + 1) * 64 * QKV_LD, &Ks[cur ^ 1][w * 512]);
            gload_lds16(vSrc + (c + 1) * 64, &Vs[cur ^ 1][w * 512]);
        }
        if (c > ct_w) continue;   // wave done computing; keep hitting barriers

        const bf16* K_ = Ks[cur];
        const bf16* V_ = Vs[cur];
        const bool diag = (c == ct_w);
        const bool two  = !(diag && !(w & 1));   // w even on diagonal: subtile 1 fully masked

        // ---- S^T[kv][q] = K Q^T for both 32-kv subtiles
        f32x16_t s0 = {}, s1 = {};
#pragma unroll
        for (int s = 0; s < 4; ++s) {
            bf16x8_t kf = ldsv8(K_ + l31 * 64 + ((16 * s + hi8) ^ swzk));
            s0 = __builtin_amdgcn_mfma_f32_32x32x16_bf16(kf, qf[s], s0, 0, 0, 0);
        }
        if (two) {
#pragma unroll
            for (int s = 0; s < 4; ++s) {
                bf16x8_t kf = ldsv8(K_ + (32 + l31) * 64 + ((16 * s + hi8) ^ swzk));
                s1 = __builtin_amdgcn_mfma_f32_32x32x16_bf16(kf, qf[s], s1, 0, 0, 0);
            }
        }

        // ---- causal mask: only the straddling subtile of the diagonal tile
        if (diag) {
            const int stm = w & 1;             // straddling subtile index
            const int kb0 = c * 64 + stm * 32 + 4 * hi;
            if (stm) {
#pragma unroll
                for (int r = 0; r < 16; ++r)
                    if (kb0 + (r & 3) + 8 * (r >> 2) > qabs) s1[r] = -1e30f;
            } else {
#pragma unroll
                for (int r = 0; r < 16; ++r)
                    if (kb0 + (r & 3) + 8 * (r >> 2) > qabs) s0[r] = -1e30f;
            }
        }

        // ---- ONE online-softmax pass per 64-kv tile (lane-local row q)
        float rm = s0[0];
#pragma unroll
        for (int r = 1; r < 16; ++r) rm = fmaxf(rm, s0[r]);
        if (two) {
#pragma unroll
            for (int r = 0; r < 16; ++r) rm = fmaxf(rm, s1[r]);
        }
        {
            u32x2_t rr = __builtin_amdgcn_permlane32_swap(
                __float_as_uint(rm), __float_as_uint(rm), false, false);
            rm = fmaxf(__uint_as_float(rr.x), __uint_as_float(rr.y));
        }
        if (!__all(rm <= mOld + THR)) {   // T13 defer-max: rescale only on real growth
            const float mN = fmaxf(mOld, rm);
            const float corr = exp2f((mOld - mN) * kE);
#pragma unroll
            for (int r = 0; r < 16; ++r) { oA[r] *= corr; oB[r] *= corr; }
            lSum *= corr;
            mOld = mN;
        }
        const float nmk = -mOld * kE;
#pragma unroll
        for (int r = 0; r < 16; ++r) s0[r] = exp2f(fmaf(s0[r], kE, nmk));
        if (two) {
#pragma unroll
            for (int r = 0; r < 16; ++r) s1[r] = exp2f(fmaf(s1[r], kE, nmk));
        }
        float rs = s0[0];
#pragma unroll
        for (int r = 1; r < 16; ++r) rs += s0[r];
        if (two) {
#pragma unroll
            for (int r = 0; r < 16; ++r) rs += s1[r];
        }
        {
            u32x2_t rr = __builtin_amdgcn_permlane32_swap(
                __float_as_uint(rs), __float_as_uint(rs), false, false);
            rs = __uint_as_float(rr.x) + __uint_as_float(rr.y);
        }
        lSum += rs;

        // ---- pack P (T12) + PV for subtile 0 (kv-slices 0,1)
        {
            unsigned pk_[8];
#pragma unroll
            for (int i = 0; i < 8; ++i) pk_[i] = pack2(s0[2 * i], s0[2 * i + 1]);
            union { unsigned u[4]; bf16x8_t v; } W0, W1;
            u32x2_t ra = __builtin_amdgcn_permlane32_swap(pk_[0], pk_[2], false, false);
            u32x2_t rb = __builtin_amdgcn_permlane32_swap(pk_[1], pk_[3], false, false);
            W0.u[0] = ra.x; W0.u[1] = rb.x; W0.u[2] = ra.y; W0.u[3] = rb.y;
            u32x2_t rc = __builtin_amdgcn_permlane32_swap(pk_[4], pk_[6], false, false);
            u32x2_t rd = __builtin_amdgcn_permlane32_swap(pk_[5], pk_[7], false, false);
            W1.u[0] = rc.x; W1.u[1] = rd.x; W1.u[2] = rc.y; W1.u[3] = rd.y;
#pragma unroll
            for (int m = 0; m < 2; ++m) {
                const int kcol = 16 * m + hi8;
                bf16x8_t vf0 = ldsv8(V_ + l31 * 64 + (kcol ^ swzk));
                oA = __builtin_amdgcn_mfma_f32_32x32x16_bf16(vf0, m ? W1.v : W0.v, oA, 0, 0, 0);
                bf16x8_t vf1 = ldsv8(V_ + (32 + l31) * 64 + (kcol ^ swzk));
                oB = __builtin_amdgcn_mfma_f32_32x32x16_bf16(vf1, m ? W1.v : W0.v, oB, 0, 0, 0);
            }
        }
        // ---- subtile 1 (kv-slices 2,3)
        if (two) {
            unsigned pk_[8];
#pragma unroll
            for (int i = 0; i < 8; ++i) pk_[i] = pack2(s1[2 * i], s1[2 * i + 1]);
            union { unsigned u[4]; bf16x8_t v; } W0, W1;
            u32x2_t ra = __builtin_amdgcn_permlane32_swap(pk_[0], pk_[2], false, false);
            u32x2_t rb = __builtin_amdgcn_permlane32_swap(pk_[1], pk_[3], false, false);
            W0.u[0] = ra.x; W0.u[1] = rb.x; W0.u[2] = ra.y; W0.u[3] = rb.y;
            u32x2_t rc = __builtin_amdgcn_permlane32_swap(pk_[4], pk_[6], false, false);
            u32x2_t rd = __builtin_amdgcn_permlane32_swap(pk_[5], pk_[7], false, false);
            W1.u[0] = rc.x; W1.u[1] = rd.x; W1.u[2] = rc.y; W1.u[3] = rd.y;
#pragma unroll
            for (int m = 0; m < 2; ++m) {
                const int kcol = 16 * (2 + m) + hi8;
                bf16x8_t vf0 = ldsv8(V_ + l31 * 64 + (kcol ^ swzk));
                oA = __builtin_amdgcn_mfma_f32_32x32x16_bf16(vf0, m ? W1.v : W0.v, oA, 0, 0, 0);
                bf16x8_t vf1 = ldsv8(V_ + (32 + l31) * 64 + (kcol ^ swzk));
                oB = __builtin_amdgcn_mfma_f32_32x32x16_bf16(vf1, m ? W1.v : W0.v, oB, 0, 0, 0);
            }
        }
    }

    // ---- normalize + store: lane owns q=qabs; reg r -> hs = (r&3)+8*(r>>2)+4*hi
    const float inv = 1.f / lSum;
    bf16* Op = O + (rowBase + qabs) * D_ + colBase;
#pragma unroll
    for (int g = 0; g < 4; ++g) {
        u32x2_t sA, sB;
        sA.x = pack2(oA[4 * g + 0] * inv, oA[4 * g + 1] * inv);
        sA.y = pack2(oA[4 * g + 2] * inv, oA[4 * g + 3] * inv);
        sB.x = pack2(oB[4 * g + 0] * inv, oB[4 * g + 1] * inv);
        sB.y = pack2(oB[4 * g + 2] * inv, oB[4 * g + 3] * inv);
        *(u32x2_t*)(Op + 8 * g + 4 * hi)      = sA;
        *(u32x2_t*)(Op + 32 + 8 * g + 4 * hi) = sB;
    }
}

// ---------------------------------------------------------------- launch
extern "C" void kernel_launch(void* const* d_in, const int* in_sizes, int n_in,
                              void* d_out, int out_size, void* d_ws, size_t ws_size,
                              hipStream_t stream)
{
    (void)in_sizes; (void)n_in; (void)out_size; (void)ws_size;
    const float* x   = (const float*)d_in[0];
    const float* wq  = (const float*)d_in[1];
    const float* wk  = (const float*)d_in[2];
    const float* wv  = (const float*)d_in[3];
    const float* wo  = (const float*)d_in[4];
    const float* bo  = (const float*)d_in[5];
    const float* w1  = (const float*)d_in[6];
    const float* b1  = (const float*)d_in[7];
    const float* w2  = (const float*)d_in[8];
    const float* b2  = (const float*)d_in[9];
    const float* g1  = (const float*)d_in[10];
    const float* be1 = (const float*)d_in[11];
    const float* g2  = (const float*)d_in[12];
    const float* be2 = (const float*)d_in[13];
    float* out = (float*)d_out;

    char* ws = (char*)d_ws;
    const size_t SLOT = (size_t)8192 * 1024 * 2;   // 16MB
    // slot plan:
    //  slot0 (16MB): xn -> attnb
    //  slots1-3 (48MB): qkv interleaved [8192,3072] -> (dead) -> xn2 at slot1
    //  slot4: vtb
    //  slots2-5 (64MB): hidden (after attention; qkv cols K/V + vtb dead)
    //  slot6-7 (32MB): x1 fp32
    bf16* xn     = (bf16*)(ws);
    bf16* attnb  = (bf16*)(ws);
    bf16* qkv    = (bf16*)(ws + SLOT);
    bf16* xn2    = (bf16*)(ws + SLOT);
    bf16* vtb    = (bf16*)(ws + 4 * SLOT);
    bf16* hidden = (bf16*)(ws + 2 * SLOT);
    float* x1    = (float*)(ws + 6 * SLOT);
    char* wpos   = ws + 6 * SLOT + (size_t)33554432;
    bf16* wqkvT = (bf16*)(wpos);                               // wq,wk,wv contiguous [3072,1024]
    bf16* wqT = (bf16*)(wpos);
    bf16* wkT = (bf16*)(wpos + (size_t)2097152);
    bf16* wvT = (bf16*)(wpos + (size_t)2 * 2097152);
    bf16* woT = (bf16*)(wpos + (size_t)3 * 2097152);
    bf16* w1T = (bf16*)(wpos + (size_t)4 * 2097152);
    bf16* w2T = (bf16*)(wpos + (size_t)4 * 2097152 + 8388608);

    transpose_cvt<<<dim3(1024), 256, 0, stream>>>(wq, wqT, 1024, 1024);
    transpose_cvt<<<dim3(1024), 256, 0, stream>>>(wk, wkT, 1024, 1024);
    transpose_cvt<<<dim3(1024), 256, 0, stream>>>(wv, wvT, 1024, 1024);
    transpose_cvt<<<dim3(1024), 256, 0, stream>>>(wo, woT, 1024, 1024);
    transpose_cvt<<<dim3(4096), 256, 0, stream>>>(w1, w1T, 1024, 4096);
    transpose_cvt<<<dim3(4096), 256, 0, stream>>>(w2, w2T, 4096, 1024);

    ln_k<<<8192, 256, 0, stream>>>(x, g1, be1, xn);

    // fused QKV GEMM: [8192,1024] @ [1024,3072] -> [8192,3072]
    gemm_bt<0, 0, 0, 1><<<1536, 256, 0, stream>>>(xn, wqkvT, nullptr, nullptr, qkv, 8192, 3072, 1024);

    vhead_transpose<<<8192, 256, 0, stream>>>(qkv, vtb);

    attn_flash<<<dim3(8, 64), 512, 0, stream>>>(qkv, vtb, attnb);

    gemm_bt<1, 0, 1, 0><<<512, 256, 0, stream>>>(attnb, woT, bo, x, x1, 8192, 1024, 1024);

    ln_k<<<8192, 256, 0, stream>>>(x1, g2, be2, xn2);

    gemm_bt<1, 1, 0, 1><<<2048, 256, 0, stream>>>(xn2, w1T, b1, nullptr, hidden, 8192, 4096, 1024);

    gemm_bt<1, 0, 1, 0><<<512, 256, 0, stream>>>(hidden, w2T, b2, x1, out, 8192, 1024, 4096);
}

// Round 5
// 535.774 us; speedup vs baseline: 1.5462x; 1.0470x over previous
//
#include <hip/hip_runtime.h>
#include <hip/hip_bf16.h>
#include <stdint.h>

typedef __hip_bfloat16 bf16;
typedef __attribute__((ext_vector_type(8))) short bf16x8_t;
typedef __attribute__((ext_vector_type(4))) float f32x4_t;
typedef __attribute__((ext_vector_type(16))) float f32x16_t;
typedef __attribute__((ext_vector_type(2))) unsigned int u32x2_t;

#define B_ 4
#define T_ 2048
#define D_ 1024
#define H_ 16
#define HS_ 64
#define QKV_LD 3072

// ---------------------------------------------------------------- helpers
__device__ __forceinline__ void gload_lds16(const void* g, void* l) {
    __builtin_amdgcn_global_load_lds(
        (const __attribute__((address_space(1))) unsigned int*)g,
        (__attribute__((address_space(3))) unsigned int*)l, 16, 0, 0);
}

__device__ __forceinline__ bf16x8_t ldsv8(const bf16* p) {
    return *(const bf16x8_t*)p;
}

__device__ __forceinline__ unsigned pack2(float a, float b) {
    union { bf16 h[2]; unsigned u; } t;
    t.h[0] = __float2bfloat16(a);
    t.h[1] = __float2bfloat16(b);
    return t.u;
}

// ---------------------------------------------------------------- weight transpose + fp32->bf16
// W[K,N] fp32 -> WT[N,K] bf16
__global__ __launch_bounds__(256) void transpose_cvt(
    const float* __restrict__ W, bf16* __restrict__ WT, int K, int N)
{
    __shared__ float tile[32][33];
    const int nbx = N >> 5;
    const int bx = blockIdx.x % nbx;   // n-tile
    const int by = blockIdx.x / nbx;   // k-tile
    const int n0 = bx << 5, k0 = by << 5;
    const int tx = threadIdx.x & 31, ty = threadIdx.x >> 5;  // ty 0..7
#pragma unroll
    for (int i = 0; i < 32; i += 8)
        tile[ty + i][tx] = W[(long)(k0 + ty + i) * N + n0 + tx];
    __syncthreads();
#pragma unroll
    for (int i = 0; i < 32; i += 8)
        WT[(long)(n0 + ty + i) * K + k0 + tx] = __float2bfloat16(tile[tx][ty + i]);
}

// ---------------------------------------------------------------- per-head V transpose (bf16)
// QKV [B*T, 3072] (V at cols 2048..3071) -> VT [B*H*HS, T]  (row = bh*64+hs, col = t)
__global__ __launch_bounds__(256) void vhead_transpose(
    const bf16* __restrict__ QKV, bf16* __restrict__ VT)
{
    __shared__ bf16 tile[32][33];
    int idx = blockIdx.x;
    const int tt  = idx & 63;   idx >>= 6;   // t-tile (T/32 = 64)
    const int hst = idx & 1;    idx >>= 1;   // hs-tile (HS/32 = 2)
    const int bh  = idx;                     // 0..63
    const int b = bh >> 4, h = bh & 15;
    const int tx = threadIdx.x & 31, ty = threadIdx.x >> 5;
    const long vrow = (long)b * T_ + tt * 32;
    const int  vcol = 2048 + h * HS_ + hst * 32;
#pragma unroll
    for (int i = 0; i < 32; i += 8)
        tile[ty + i][tx] = QKV[(vrow + ty + i) * QKV_LD + vcol + tx];
    __syncthreads();
    const long orow = (long)bh * HS_ + hst * 32;
#pragma unroll
    for (int i = 0; i < 32; i += 8)
        VT[(orow + ty + i) * T_ + tt * 32 + tx] = tile[tx][ty + i];
}

// ---------------------------------------------------------------- LayerNorm (fp32 in -> bf16 out)
__global__ __launch_bounds__(256) void ln_k(
    const float* __restrict__ x, const float* __restrict__ g,
    const float* __restrict__ be, bf16* __restrict__ out)
{
    const long row = blockIdx.x;
    const int t = threadIdx.x;
    const float4 v = ((const float4*)(x + row * D_))[t];
    float s  = v.x + v.y + v.z + v.w;
    float s2 = v.x * v.x + v.y * v.y + v.z * v.z + v.w * v.w;
#pragma unroll
    for (int m = 1; m < 64; m <<= 1) {
        s  += __shfl_xor(s, m, 64);
        s2 += __shfl_xor(s2, m, 64);
    }
    __shared__ float red[8];
    const int wv = t >> 6, ln = t & 63;
    if (ln == 0) { red[wv] = s; red[4 + wv] = s2; }
    __syncthreads();
    s  = red[0] + red[1] + red[2] + red[3];
    s2 = red[4] + red[5] + red[6] + red[7];
    const float mu  = s * (1.f / (float)D_);
    const float var = s2 * (1.f / (float)D_) - mu * mu;
    const float rs  = rsqrtf(var + 1e-5f);
    const float4 gv = ((const float4*)g)[t];
    const float4 bv = ((const float4*)be)[t];
    union { bf16 h[4]; short4 s4; } u;
    u.h[0] = __float2bfloat16((v.x - mu) * rs * gv.x + bv.x);
    u.h[1] = __float2bfloat16((v.y - mu) * rs * gv.y + bv.y);
    u.h[2] = __float2bfloat16((v.z - mu) * rs * gv.z + bv.z);
    u.h[3] = __float2bfloat16((v.w - mu) * rs * gv.w + bv.w);
    ((short4*)(out + row * D_))[t] = u.s4;
}

// ---------------------------------------------------------------- GEMM v2: 256x128 tile, 8 waves,
// BK=64 double-buffered (96KB LDS), counted-vmcnt pipeline (T3+T4), T2 XOR swizzle
// (pre-swizzled global source per rule #21), T5 setprio, T1 XCD swizzle.
// C[M,N] = A[M,K] @ BT[N,K]^T ; epilogue bias/relu/fp32-residual/bf16-or-fp32 out.
template<int HAS_BIAS, int RELU, int HAS_RES, int OUT_BF16>
__global__ __launch_bounds__(512, 1) void gemm2(
    const bf16* __restrict__ A, const bf16* __restrict__ BT,
    const float* __restrict__ bias, const float* __restrict__ res,
    void* __restrict__ Cout, int M, int N, int K)
{
    __shared__ bf16 As[2][256 * 64];
    __shared__ bf16 Bs[2][128 * 64];
    const int tid  = threadIdx.x;
    const int w    = tid >> 6;
    const int lane = tid & 63;
    const int wm = w >> 1, wn = w & 1;        // wave tile: rows wm*64, cols wn*64
    const int nbn = N >> 7;
    const int cpx = gridDim.x >> 3;           // blocks per XCD (grid % 8 == 0)
    const int bid = (blockIdx.x & 7) * cpx + (blockIdx.x >> 3);
    const int bm = bid / nbn, bn = bid % nbn;
    const int row0 = bm << 8, col0 = bn << 7;

    // staging sources: load l covers flat = l*512+tid -> row = flat>>3, chunk-slot = flat&7.
    // Global col pre-swizzled (chunk ^ (row&7)) so the LINEAR gload_lds write lands swizzled.
    const bf16* aS0; const bf16* aS1; const bf16* aS2; const bf16* aS3;
    const bf16* bS0; const bf16* bS1;
    {
        int f0 = tid,        r0 = f0 >> 3, c0 = ((f0 & 7) ^ (r0 & 7)) << 3;
        int f1 = 512 + tid,  r1 = f1 >> 3, c1 = ((f1 & 7) ^ (r1 & 7)) << 3;
        int f2 = 1024 + tid, r2 = f2 >> 3, c2 = ((f2 & 7) ^ (r2 & 7)) << 3;
        int f3 = 1536 + tid, r3 = f3 >> 3, c3 = ((f3 & 7) ^ (r3 & 7)) << 3;
        aS0 = A + (long)(row0 + r0) * K + c0;
        aS1 = A + (long)(row0 + r1) * K + c1;
        aS2 = A + (long)(row0 + r2) * K + c2;
        aS3 = A + (long)(row0 + r3) * K + c3;
        bS0 = BT + (long)(col0 + r0) * K + c0;
        bS1 = BT + (long)(col0 + r1) * K + c1;
    }
    const int wbase = w * 64;   // wave-uniform lds flat base component

#define STAGE(buf, kt) do {                                              \
        const long ko_ = (long)(kt) * 64;                                \
        gload_lds16(aS0 + ko_, &As[buf][(0 * 512 + wbase) * 8]);         \
        gload_lds16(aS1 + ko_, &As[buf][(1 * 512 + wbase) * 8]);         \
        gload_lds16(aS2 + ko_, &As[buf][(2 * 512 + wbase) * 8]);         \
        gload_lds16(aS3 + ko_, &As[buf][(3 * 512 + wbase) * 8]);         \
        gload_lds16(bS0 + ko_, &Bs[buf][(0 * 512 + wbase) * 8]);         \
        gload_lds16(bS1 + ko_, &Bs[buf][(1 * 512 + wbase) * 8]);         \
    } while (0)

    f32x4_t acc[4][4] = {};
    const int fr = lane & 15;        // fragment row
    const int fq = lane >> 4;        // k-quarter (chunk within k-step)
    const int nt = K >> 6;

    // prologue: stage tiles 0 and 1
    STAGE(0, 0);
    STAGE(1, 1);

    for (int t = 0; t < nt; ++t) {
        const int cur = t & 1;
        if (t < nt - 1) asm volatile("s_waitcnt vmcnt(6)" ::: "memory");
        else            asm volatile("s_waitcnt vmcnt(0)" ::: "memory");
        __builtin_amdgcn_s_barrier();      // buf[cur] fully staged, all waves

        bf16x8_t a[2][4], b[2][4];
#pragma unroll
        for (int ks = 0; ks < 2; ++ks) {
#pragma unroll
            for (int m = 0; m < 4; ++m) {
                const int r = wm * 64 + m * 16 + fr;
                const int ch = ks * 4 + fq;
                a[ks][m] = ldsv8(&As[cur][r * 64 + ((ch ^ (r & 7)) << 3)]);
            }
#pragma unroll
            for (int n = 0; n < 4; ++n) {
                const int r = wn * 64 + n * 16 + fr;
                const int ch = ks * 4 + fq;
                b[ks][n] = ldsv8(&Bs[cur][r * 64 + ((ch ^ (r & 7)) << 3)]);
            }
        }
        asm volatile("s_waitcnt lgkmcnt(0)" ::: "memory");   // reads done before overwrite
        __builtin_amdgcn_sched_barrier(0);                   // rule #18
        __builtin_amdgcn_s_barrier();      // all waves done reading buf[cur]

        if (t + 2 < nt) STAGE(cur, t + 2); // async stage into freed buffer (stays in flight)

        __builtin_amdgcn_s_setprio(1);
#pragma unroll
        for (int m = 0; m < 4; ++m)
#pragma unroll
            for (int n = 0; n < 4; ++n) {
                acc[m][n] = __builtin_amdgcn_mfma_f32_16x16x32_bf16(a[0][m], b[0][n], acc[m][n], 0, 0, 0);
                acc[m][n] = __builtin_amdgcn_mfma_f32_16x16x32_bf16(a[1][m], b[1][n], acc[m][n], 0, 0, 0);
            }
        __builtin_amdgcn_s_setprio(0);
    }
#undef STAGE

    // epilogue: D layout col=lane&15, row=(lane>>4)*4+reg
    const int orow = fq << 2;
#pragma unroll
    for (int m = 0; m < 4; ++m) {
        const int rbase = row0 + wm * 64 + m * 16 + orow;
#pragma unroll
        for (int n = 0; n < 4; ++n) {
            const int c = col0 + wn * 64 + n * 16 + fr;
            float bv = 0.f;
            if (HAS_BIAS) bv = bias[c];
#pragma unroll
            for (int r = 0; r < 4; ++r) {
                float v = acc[m][n][r] + bv;
                if (RELU) v = fmaxf(v, 0.f);
                if (HAS_RES) v += res[(long)(rbase + r) * N + c];
                if (OUT_BF16)
                    ((bf16*)Cout)[(long)(rbase + r) * N + c] = __float2bfloat16(v);
                else
                    ((float*)Cout)[(long)(rbase + r) * N + c] = v;
            }
        }
    }
}

// ---------------------------------------------------------------- flash attention (causal) v4
// Swapped-operand 32x32x16: S^T = mfma(K,Q) -> col=q=lane&31, softmax lane-local.
__global__ __launch_bounds__(512, 2) void attn_flash(
    const bf16* __restrict__ QKV, const bf16* __restrict__ VT,
    bf16* __restrict__ O)
{
    __shared__ bf16 Ks[2][64 * 64];   // K tile [kv][hs], XOR-swizzled
    __shared__ bf16 Vs[2][64 * 64];   // V^T tile [hs][kv], XOR-swizzled

    const int tid = threadIdx.x;
    const int w   = tid >> 6;          // wave 0..7
    const int ln  = tid & 63;
    const int l31 = ln & 31;
    const int hi  = ln >> 5;
    const int hi8 = hi << 3;

    const int qb = 7 - (int)blockIdx.x;   // heavy q-blocks first (per bh)
    const int bh = blockIdx.y;
    const long rowBase = (long)(bh >> 4) * T_;
    const int colBase = (bh & 15) * HS_;

    const int qwbase = qb * 256 + w * 32;   // wave's first q row
    const int qabs   = qwbase + l31;        // this lane's q row
    const int ctb  = qb * 4 + 3;            // last kv tile staged by block
    const int ct_w = qb * 4 + (w >> 1);     // wave's diagonal kv tile

    // Q fragments (B-operand): lane holds Q[q=l31][hs = 16s + hi8 + j]
    const bf16* qp = QKV + (rowBase + qabs) * QKV_LD + colBase + hi8;
    bf16x8_t qf[4];
#pragma unroll
    for (int s = 0; s < 4; ++s) qf[s] = *(const bf16x8_t*)(qp + 16 * s);

    f32x16_t oA = {}, oB = {};   // O^T accum: col=q=l31, row hs=(r&3)+8*(r>>2)+4*hi (+32 for oB)
    float mOld = -1e30f, lSum = 0.f;
    const float kE  = 0.0450842200278f;   // (1/32) * log2(e)
    const float THR = 256.0f;             // defer-max threshold (raw S units, = e^8 bound)

    // staging: thread t -> row t>>3, chunk pre-swizzled so linear LDS write lands swizzled
    const int srow = tid >> 3;                              // 0..63
    const int schunk = (((tid & 7) ^ (srow & 7)) << 3);     // elements
    const bf16* kSrc = QKV + (rowBase + srow) * QKV_LD + 1024 + colBase + schunk;
    const bf16* vSrc = VT + ((long)bh * HS_ + srow) * T_ + schunk;

    // prologue: stage tile 0 into buffer 0
    gload_lds16(kSrc, &Ks[0][w * 512]);
    gload_lds16(vSrc, &Vs[0][w * 512]);

    const int swzk = (l31 & 7) << 3;

    for (int c = 0; c <= ctb; ++c) {
        const int cur = c & 1;
        __syncthreads();   // buf[cur] staged (barrier drains vmcnt), prev reads done

        if (c < ctb) {     // prefetch next tile
            gload_lds16(kSrc + (long)(c + 1) * 64 * QKV_LD, &Ks[cur ^ 1][w * 512]);
            gload_lds16(vSrc + (c + 1) * 64, &Vs[cur ^ 1][w * 512]);
        }
        if (c > ct_w) continue;   // wave done computing; keep hitting barriers

        const bf16* K_ = Ks[cur];
        const bf16* V_ = Vs[cur];
        const bool diag = (c == ct_w);
        const bool two  = !(diag && !(w & 1));   // w even on diagonal: subtile 1 fully masked

        // ---- S^T[kv][q] = K Q^T for both 32-kv subtiles
        f32x16_t s0 = {}, s1 = {};
#pragma unroll
        for (int s = 0; s < 4; ++s) {
            bf16x8_t kf = ldsv8(K_ + l31 * 64 + ((16 * s + hi8) ^ swzk));
            s0 = __builtin_amdgcn_mfma_f32_32x32x16_bf16(kf, qf[s], s0, 0, 0, 0);
        }
        if (two) {
#pragma unroll
            for (int s = 0; s < 4; ++s) {
                bf16x8_t kf = ldsv8(K_ + (32 + l31) * 64 + ((16 * s + hi8) ^ swzk));
                s1 = __builtin_amdgcn_mfma_f32_32x32x16_bf16(kf, qf[s], s1, 0, 0, 0);
            }
        }

        // ---- causal mask: only the straddling subtile of the diagonal tile
        if (diag) {
            const int stm = w & 1;             // straddling subtile index
            const int kb0 = c * 64 + stm * 32 + 4 * hi;
            if (stm) {
#pragma unroll
                for (int r = 0; r < 16; ++r)
                    if (kb0 + (r & 3) + 8 * (r >> 2) > qabs) s1[r] = -1e30f;
            } else {
#pragma unroll
                for (int r = 0; r < 16; ++r)
                    if (kb0 + (r & 3) + 8 * (r >> 2) > qabs) s0[r] = -1e30f;
            }
        }

        // ---- ONE online-softmax pass per 64-kv tile (lane-local row q)
        float rm = s0[0];
#pragma unroll
        for (int r = 1; r < 16; ++r) rm = fmaxf(rm, s0[r]);
        if (two) {
#pragma unroll
            for (int r = 0; r < 16; ++r) rm = fmaxf(rm, s1[r]);
        }
        {
            u32x2_t rr = __builtin_amdgcn_permlane32_swap(
                __float_as_uint(rm), __float_as_uint(rm), false, false);
            rm = fmaxf(__uint_as_float(rr.x), __uint_as_float(rr.y));
        }
        if (!__all(rm <= mOld + THR)) {   // T13 defer-max: rescale only on real growth
            const float mN = fmaxf(mOld, rm);
            const float corr = exp2f((mOld - mN) * kE);
#pragma unroll
            for (int r = 0; r < 16; ++r) { oA[r] *= corr; oB[r] *= corr; }
            lSum *= corr;
            mOld = mN;
        }
        const float nmk = -mOld * kE;
#pragma unroll
        for (int r = 0; r < 16; ++r) s0[r] = exp2f(fmaf(s0[r], kE, nmk));
        if (two) {
#pragma unroll
            for (int r = 0; r < 16; ++r) s1[r] = exp2f(fmaf(s1[r], kE, nmk));
        }
        float rs = s0[0];
#pragma unroll
        for (int r = 1; r < 16; ++r) rs += s0[r];
        if (two) {
#pragma unroll
            for (int r = 0; r < 16; ++r) rs += s1[r];
        }
        {
            u32x2_t rr = __builtin_amdgcn_permlane32_swap(
                __float_as_uint(rs), __float_as_uint(rs), false, false);
            rs = __uint_as_float(rr.x) + __uint_as_float(rr.y);
        }
        lSum += rs;

        // ---- pack P (T12) + PV for subtile 0 (kv-slices 0,1)
        {
            unsigned pk_[8];
#pragma unroll
            for (int i = 0; i < 8; ++i) pk_[i] = pack2(s0[2 * i], s0[2 * i + 1]);
            union { unsigned u[4]; bf16x8_t v; } W0, W1;
            u32x2_t ra = __builtin_amdgcn_permlane32_swap(pk_[0], pk_[2], false, false);
            u32x2_t rb = __builtin_amdgcn_permlane32_swap(pk_[1], pk_[3], false, false);
            W0.u[0] = ra.x; W0.u[1] = rb.x; W0.u[2] = ra.y; W0.u[3] = rb.y;
            u32x2_t rc = __builtin_amdgcn_permlane32_swap(pk_[4], pk_[6], false, false);
            u32x2_t rd = __builtin_amdgcn_permlane32_swap(pk_[5], pk_[7], false, false);
            W1.u[0] = rc.x; W1.u[1] = rd.x; W1.u[2] = rc.y; W1.u[3] = rd.y;
#pragma unroll
            for (int m = 0; m < 2; ++m) {
                const int kcol = 16 * m + hi8;
                bf16x8_t vf0 = ldsv8(V_ + l31 * 64 + (kcol ^ swzk));
                oA = __builtin_amdgcn_mfma_f32_32x32x16_bf16(vf0, m ? W1.v : W0.v, oA, 0, 0, 0);
                bf16x8_t vf1 = ldsv8(V_ + (32 + l31) * 64 + (kcol ^ swzk));
                oB = __builtin_amdgcn_mfma_f32_32x32x16_bf16(vf1, m ? W1.v : W0.v, oB, 0, 0, 0);
            }
        }
        // ---- subtile 1 (kv-slices 2,3)
        if (two) {
            unsigned pk_[8];
#pragma unroll
            for (int i = 0; i < 8; ++i) pk_[i] = pack2(s1[2 * i], s1[2 * i + 1]);
            union { unsigned u[4]; bf16x8_t v; } W0, W1;
            u32x2_t ra = __builtin_amdgcn_permlane32_swap(pk_[0], pk_[2], false, false);
            u32x2_t rb = __builtin_amdgcn_permlane32_swap(pk_[1], pk_[3], false, false);
            W0.u[0] = ra.x; W0.u[1] = rb.x; W0.u[2] = ra.y; W0.u[3] = rb.y;
            u32x2_t rc = __builtin_amdgcn_permlane32_swap(pk_[4], pk_[6], false, false);
            u32x2_t rd = __builtin_amdgcn_permlane32_swap(pk_[5], pk_[7], false, false);
            W1.u[0] = rc.x; W1.u[1] = rd.x; W1.u[2] = rc.y; W1.u[3] = rd.y;
#pragma unroll
            for (int m = 0; m < 2; ++m) {
                const int kcol = 16 * (2 + m) + hi8;
                bf16x8_t vf0 = ldsv8(V_ + l31 * 64 + (kcol ^ swzk));
                oA = __builtin_amdgcn_mfma_f32_32x32x16_bf16(vf0, m ? W1.v : W0.v, oA, 0, 0, 0);
                bf16x8_t vf1 = ldsv8(V_ + (32 + l31) * 64 + (kcol ^ swzk));
                oB = __builtin_amdgcn_mfma_f32_32x32x16_bf16(vf1, m ? W1.v : W0.v, oB, 0, 0, 0);
            }
        }
    }

    // ---- normalize + store: lane owns q=qabs; reg r -> hs = (r&3)+8*(r>>2)+4*hi
    const float inv = 1.f / lSum;
    bf16* Op = O + (rowBase + qabs) * D_ + colBase;
#pragma unroll
    for (int g = 0; g < 4; ++g) {
        u32x2_t sA, sB;
        sA.x = pack2(oA[4 * g + 0] * inv, oA[4 * g + 1] * inv);
        sA.y = pack2(oA[4 * g + 2] * inv, oA[4 * g + 3] * inv);
        sB.x = pack2(oB[4 * g + 0] * inv, oB[4 * g + 1] * inv);
        sB.y = pack2(oB[4 * g + 2] * inv, oB[4 * g + 3] * inv);
        *(u32x2_t*)(Op + 8 * g + 4 * hi)      = sA;
        *(u32x2_t*)(Op + 32 + 8 * g + 4 * hi) = sB;
    }
}

// ---------------------------------------------------------------- launch
extern "C" void kernel_launch(void* const* d_in, const int* in_sizes, int n_in,
                              void* d_out, int out_size, void* d_ws, size_t ws_size,
                              hipStream_t stream)
{
    (void)in_sizes; (void)n_in; (void)out_size; (void)ws_size;
    const float* x   = (const float*)d_in[0];
    const float* wq  = (const float*)d_in[1];
    const float* wk  = (const float*)d_in[2];
    const float* wv  = (const float*)d_in[3];
    const float* wo  = (const float*)d_in[4];
    const float* bo  = (const float*)d_in[5];
    const float* w1  = (const float*)d_in[6];
    const float* b1  = (const float*)d_in[7];
    const float* w2  = (const float*)d_in[8];
    const float* b2  = (const float*)d_in[9];
    const float* g1  = (const float*)d_in[10];
    const float* be1 = (const float*)d_in[11];
    const float* g2  = (const float*)d_in[12];
    const float* be2 = (const float*)d_in[13];
    float* out = (float*)d_out;

    char* ws = (char*)d_ws;
    const size_t SLOT = (size_t)8192 * 1024 * 2;   // 16MB
    bf16* xn     = (bf16*)(ws);
    bf16* attnb  = (bf16*)(ws);
    bf16* qkv    = (bf16*)(ws + SLOT);
    bf16* xn2    = (bf16*)(ws + SLOT);
    bf16* vtb    = (bf16*)(ws + 4 * SLOT);
    bf16* hidden = (bf16*)(ws + 2 * SLOT);
    float* x1    = (float*)(ws + 6 * SLOT);
    char* wpos   = ws + 6 * SLOT + (size_t)33554432;
    bf16* wqkvT = (bf16*)(wpos);                               // wq,wk,wv contiguous [3072,1024]
    bf16* wqT = (bf16*)(wpos);
    bf16* wkT = (bf16*)(wpos + (size_t)2097152);
    bf16* wvT = (bf16*)(wpos + (size_t)2 * 2097152);
    bf16* woT = (bf16*)(wpos + (size_t)3 * 2097152);
    bf16* w1T = (bf16*)(wpos + (size_t)4 * 2097152);
    bf16* w2T = (bf16*)(wpos + (size_t)4 * 2097152 + 8388608);

    transpose_cvt<<<dim3(1024), 256, 0, stream>>>(wq, wqT, 1024, 1024);
    transpose_cvt<<<dim3(1024), 256, 0, stream>>>(wk, wkT, 1024, 1024);
    transpose_cvt<<<dim3(1024), 256, 0, stream>>>(wv, wvT, 1024, 1024);
    transpose_cvt<<<dim3(1024), 256, 0, stream>>>(wo, woT, 1024, 1024);
    transpose_cvt<<<dim3(4096), 256, 0, stream>>>(w1, w1T, 1024, 4096);
    transpose_cvt<<<dim3(4096), 256, 0, stream>>>(w2, w2T, 4096, 1024);

    ln_k<<<8192, 256, 0, stream>>>(x, g1, be1, xn);

    // fused QKV GEMM: [8192,1024] @ [1024,3072] -> [8192,3072]
    gemm2<0, 0, 0, 1><<<768, 512, 0, stream>>>(xn, wqkvT, nullptr, nullptr, qkv, 8192, 3072, 1024);

    vhead_transpose<<<8192, 256, 0, stream>>>(qkv, vtb);

    attn_flash<<<dim3(8, 64), 512, 0, stream>>>(qkv, vtb, attnb);

    gemm2<1, 0, 1, 0><<<256, 512, 0, stream>>>(attnb, woT, bo, x, x1, 8192, 1024, 1024);

    ln_k<<<8192, 256, 0, stream>>>(x1, g2, be2, xn2);

    gemm2<1, 1, 0, 1><<<1024, 512, 0, stream>>>(xn2, w1T, b1, nullptr, hidden, 8192, 4096, 1024);

    gemm2<1, 0, 1, 0><<<256, 512, 0, stream>>>(hidden, w2T, b2, x1, out, 8192, 1024, 4096);
}

// Round 6
// 504.347 us; speedup vs baseline: 1.6426x; 1.0623x over previous
//
#include <hip/hip_runtime.h>
#include <hip/hip_bf16.h>
#include <stdint.h>

typedef __hip_bfloat16 bf16;
typedef __attribute__((ext_vector_type(8))) short bf16x8_t;
typedef __attribute__((ext_vector_type(4))) float f32x4_t;
typedef __attribute__((ext_vector_type(16))) float f32x16_t;
typedef __attribute__((ext_vector_type(2))) unsigned int u32x2_t;

#define B_ 4
#define T_ 2048
#define D_ 1024
#define H_ 16
#define HS_ 64
#define QKV_LD 3072

// ---------------------------------------------------------------- helpers
__device__ __forceinline__ void gload_lds16(const void* g, void* l) {
    __builtin_amdgcn_global_load_lds(
        (const __attribute__((address_space(1))) unsigned int*)g,
        (__attribute__((address_space(3))) unsigned int*)l, 16, 0, 0);
}

__device__ __forceinline__ bf16x8_t ldsv8(const bf16* p) {
    return *(const bf16x8_t*)p;
}

__device__ __forceinline__ unsigned pack2(float a, float b) {
    union { bf16 h[2]; unsigned u; } t;
    t.h[0] = __float2bfloat16(a);
    t.h[1] = __float2bfloat16(b);
    return t.u;
}

// ---------------------------------------------------------------- weight transpose + fp32->bf16
// W[K,N] fp32 -> WT[N,K] bf16
__global__ __launch_bounds__(256) void transpose_cvt(
    const float* __restrict__ W, bf16* __restrict__ WT, int K, int N)
{
    __shared__ float tile[32][33];
    const int nbx = N >> 5;
    const int bx = blockIdx.x % nbx;   // n-tile
    const int by = blockIdx.x / nbx;   // k-tile
    const int n0 = bx << 5, k0 = by << 5;
    const int tx = threadIdx.x & 31, ty = threadIdx.x >> 5;  // ty 0..7
#pragma unroll
    for (int i = 0; i < 32; i += 8)
        tile[ty + i][tx] = W[(long)(k0 + ty + i) * N + n0 + tx];
    __syncthreads();
#pragma unroll
    for (int i = 0; i < 32; i += 8)
        WT[(long)(n0 + ty + i) * K + k0 + tx] = __float2bfloat16(tile[tx][ty + i]);
}

// ---------------------------------------------------------------- per-head V transpose (bf16)
// QKV [B*T, 3072] (V at cols 2048..3071) -> VT [B*H*HS, T]  (row = bh*64+hs, col = t)
__global__ __launch_bounds__(256) void vhead_transpose(
    const bf16* __restrict__ QKV, bf16* __restrict__ VT)
{
    __shared__ bf16 tile[32][33];
    int idx = blockIdx.x;
    const int tt  = idx & 63;   idx >>= 6;   // t-tile (T/32 = 64)
    const int hst = idx & 1;    idx >>= 1;   // hs-tile (HS/32 = 2)
    const int bh  = idx;                     // 0..63
    const int b = bh >> 4, h = bh & 15;
    const int tx = threadIdx.x & 31, ty = threadIdx.x >> 5;
    const long vrow = (long)b * T_ + tt * 32;
    const int  vcol = 2048 + h * HS_ + hst * 32;
#pragma unroll
    for (int i = 0; i < 32; i += 8)
        tile[ty + i][tx] = QKV[(vrow + ty + i) * QKV_LD + vcol + tx];
    __syncthreads();
    const long orow = (long)bh * HS_ + hst * 32;
#pragma unroll
    for (int i = 0; i < 32; i += 8)
        VT[(orow + ty + i) * T_ + tt * 32 + tx] = tile[tx][ty + i];
}

// ---------------------------------------------------------------- LayerNorm (fp32 in -> bf16 out)
__global__ __launch_bounds__(256) void ln_k(
    const float* __restrict__ x, const float* __restrict__ g,
    const float* __restrict__ be, bf16* __restrict__ out)
{
    const long row = blockIdx.x;
    const int t = threadIdx.x;
    const float4 v = ((const float4*)(x + row * D_))[t];
    float s  = v.x + v.y + v.z + v.w;
    float s2 = v.x * v.x + v.y * v.y + v.z * v.z + v.w * v.w;
#pragma unroll
    for (int m = 1; m < 64; m <<= 1) {
        s  += __shfl_xor(s, m, 64);
        s2 += __shfl_xor(s2, m, 64);
    }
    __shared__ float red[8];
    const int wv = t >> 6, ln = t & 63;
    if (ln == 0) { red[wv] = s; red[4 + wv] = s2; }
    __syncthreads();
    s  = red[0] + red[1] + red[2] + red[3];
    s2 = red[4] + red[5] + red[6] + red[7];
    const float mu  = s * (1.f / (float)D_);
    const float var = s2 * (1.f / (float)D_) - mu * mu;
    const float rs  = rsqrtf(var + 1e-5f);
    const float4 gv = ((const float4*)g)[t];
    const float4 bv = ((const float4*)be)[t];
    union { bf16 h[4]; short4 s4; } u;
    u.h[0] = __float2bfloat16((v.x - mu) * rs * gv.x + bv.x);
    u.h[1] = __float2bfloat16((v.y - mu) * rs * gv.y + bv.y);
    u.h[2] = __float2bfloat16((v.z - mu) * rs * gv.z + bv.z);
    u.h[3] = __float2bfloat16((v.w - mu) * rs * gv.w + bv.w);
    ((short4*)(out + row * D_))[t] = u.s4;
}

// ---------------------------------------------------------------- GEMM v2: 256x128 tile, 8 waves,
// BK=64 double-buffered (96KB LDS), counted-vmcnt pipeline (T3+T4), T2 XOR swizzle
// (pre-swizzled global source per rule #21), T5 setprio, T1 XCD swizzle.
template<int HAS_BIAS, int RELU, int HAS_RES, int OUT_BF16>
__global__ __launch_bounds__(512, 1) void gemm2(
    const bf16* __restrict__ A, const bf16* __restrict__ BT,
    const float* __restrict__ bias, const float* __restrict__ res,
    void* __restrict__ Cout, int M, int N, int K)
{
    __shared__ bf16 As[2][256 * 64];
    __shared__ bf16 Bs[2][128 * 64];
    const int tid  = threadIdx.x;
    const int w    = tid >> 6;
    const int lane = tid & 63;
    const int wm = w >> 1, wn = w & 1;        // wave tile: rows wm*64, cols wn*64
    const int nbn = N >> 7;
    const int cpx = gridDim.x >> 3;           // blocks per XCD (grid % 8 == 0)
    const int bid = (blockIdx.x & 7) * cpx + (blockIdx.x >> 3);
    const int bm = bid / nbn, bn = bid % nbn;
    const int row0 = bm << 8, col0 = bn << 7;

    const bf16* aS0; const bf16* aS1; const bf16* aS2; const bf16* aS3;
    const bf16* bS0; const bf16* bS1;
    {
        int f0 = tid,        r0 = f0 >> 3, c0 = ((f0 & 7) ^ (r0 & 7)) << 3;
        int f1 = 512 + tid,  r1 = f1 >> 3, c1 = ((f1 & 7) ^ (r1 & 7)) << 3;
        int f2 = 1024 + tid, r2 = f2 >> 3, c2 = ((f2 & 7) ^ (r2 & 7)) << 3;
        int f3 = 1536 + tid, r3 = f3 >> 3, c3 = ((f3 & 7) ^ (r3 & 7)) << 3;
        aS0 = A + (long)(row0 + r0) * K + c0;
        aS1 = A + (long)(row0 + r1) * K + c1;
        aS2 = A + (long)(row0 + r2) * K + c2;
        aS3 = A + (long)(row0 + r3) * K + c3;
        bS0 = BT + (long)(col0 + r0) * K + c0;
        bS1 = BT + (long)(col0 + r1) * K + c1;
    }
    const int wbase = w * 64;

#define STAGE(buf, kt) do {                                              \
        const long ko_ = (long)(kt) * 64;                                \
        gload_lds16(aS0 + ko_, &As[buf][(0 * 512 + wbase) * 8]);         \
        gload_lds16(aS1 + ko_, &As[buf][(1 * 512 + wbase) * 8]);         \
        gload_lds16(aS2 + ko_, &As[buf][(2 * 512 + wbase) * 8]);         \
        gload_lds16(aS3 + ko_, &As[buf][(3 * 512 + wbase) * 8]);         \
        gload_lds16(bS0 + ko_, &Bs[buf][(0 * 512 + wbase) * 8]);         \
        gload_lds16(bS1 + ko_, &Bs[buf][(1 * 512 + wbase) * 8]);         \
    } while (0)

    f32x4_t acc[4][4] = {};
    const int fr = lane & 15;
    const int fq = lane >> 4;
    const int nt = K >> 6;

    STAGE(0, 0);
    STAGE(1, 1);

    for (int t = 0; t < nt; ++t) {
        const int cur = t & 1;
        if (t < nt - 1) asm volatile("s_waitcnt vmcnt(6)" ::: "memory");
        else            asm volatile("s_waitcnt vmcnt(0)" ::: "memory");
        __builtin_amdgcn_s_barrier();

        bf16x8_t a[2][4], b[2][4];
#pragma unroll
        for (int ks = 0; ks < 2; ++ks) {
#pragma unroll
            for (int m = 0; m < 4; ++m) {
                const int r = wm * 64 + m * 16 + fr;
                const int ch = ks * 4 + fq;
                a[ks][m] = ldsv8(&As[cur][r * 64 + ((ch ^ (r & 7)) << 3)]);
            }
#pragma unroll
            for (int n = 0; n < 4; ++n) {
                const int r = wn * 64 + n * 16 + fr;
                const int ch = ks * 4 + fq;
                b[ks][n] = ldsv8(&Bs[cur][r * 64 + ((ch ^ (r & 7)) << 3)]);
            }
        }
        asm volatile("s_waitcnt lgkmcnt(0)" ::: "memory");
        __builtin_amdgcn_sched_barrier(0);
        __builtin_amdgcn_s_barrier();

        if (t + 2 < nt) STAGE(cur, t + 2);

        __builtin_amdgcn_s_setprio(1);
#pragma unroll
        for (int m = 0; m < 4; ++m)
#pragma unroll
            for (int n = 0; n < 4; ++n) {
                acc[m][n] = __builtin_amdgcn_mfma_f32_16x16x32_bf16(a[0][m], b[0][n], acc[m][n], 0, 0, 0);
                acc[m][n] = __builtin_amdgcn_mfma_f32_16x16x32_bf16(a[1][m], b[1][n], acc[m][n], 0, 0, 0);
            }
        __builtin_amdgcn_s_setprio(0);
    }
#undef STAGE

    const int orow = fq << 2;
#pragma unroll
    for (int m = 0; m < 4; ++m) {
        const int rbase = row0 + wm * 64 + m * 16 + orow;
#pragma unroll
        for (int n = 0; n < 4; ++n) {
            const int c = col0 + wn * 64 + n * 16 + fr;
            float bv = 0.f;
            if (HAS_BIAS) bv = bias[c];
#pragma unroll
            for (int r = 0; r < 4; ++r) {
                float v = acc[m][n][r] + bv;
                if (RELU) v = fmaxf(v, 0.f);
                if (HAS_RES) v += res[(long)(rbase + r) * N + c];
                if (OUT_BF16)
                    ((bf16*)Cout)[(long)(rbase + r) * N + c] = __float2bfloat16(v);
                else
                    ((float*)Cout)[(long)(rbase + r) * N + c] = v;
            }
        }
    }
}

// ---------------------------------------------------------------- attention tile compute
// (shared by both q-tiles of a block; all indices statically unrolled)
__device__ __forceinline__ void attn_tile(
    const bf16* K_, const bf16* V_, const bf16x8_t (&qf)[4],
    f32x16_t& oA, f32x16_t& oB, float& mOld, float& lSum,
    int c, int ct_w, int qabs, int w, int l31, int hi, int hi8, int swzk)
{
    const float kE  = 0.0450842200278f;   // (1/32) * log2(e)
    const float THR = 256.0f;             // defer-max threshold (e^8 bound)
    const bool diag = (c == ct_w);
    const bool two  = !(diag && !(w & 1));

    // ---- S^T[kv][q] = K Q^T for both 32-kv subtiles
    f32x16_t s0 = {}, s1 = {};
#pragma unroll
    for (int s = 0; s < 4; ++s) {
        bf16x8_t kf = ldsv8(K_ + l31 * 64 + ((16 * s + hi8) ^ swzk));
        s0 = __builtin_amdgcn_mfma_f32_32x32x16_bf16(kf, qf[s], s0, 0, 0, 0);
    }
    if (two) {
#pragma unroll
        for (int s = 0; s < 4; ++s) {
            bf16x8_t kf = ldsv8(K_ + (32 + l31) * 64 + ((16 * s + hi8) ^ swzk));
            s1 = __builtin_amdgcn_mfma_f32_32x32x16_bf16(kf, qf[s], s1, 0, 0, 0);
        }
    }

    // ---- causal mask: straddling subtile of the diagonal tile only
    if (diag) {
        const int stm = w & 1;
        const int kb0 = c * 64 + stm * 32 + 4 * hi;
        if (stm) {
#pragma unroll
            for (int r = 0; r < 16; ++r)
                if (kb0 + (r & 3) + 8 * (r >> 2) > qabs) s1[r] = -1e30f;
        } else {
#pragma unroll
            for (int r = 0; r < 16; ++r)
                if (kb0 + (r & 3) + 8 * (r >> 2) > qabs) s0[r] = -1e30f;
        }
    }

    // ---- online softmax (lane-local row q), one pass per 64-kv tile
    float rm = s0[0];
#pragma unroll
    for (int r = 1; r < 16; ++r) rm = fmaxf(rm, s0[r]);
    if (two) {
#pragma unroll
        for (int r = 0; r < 16; ++r) rm = fmaxf(rm, s1[r]);
    }
    {
        u32x2_t rr = __builtin_amdgcn_permlane32_swap(
            __float_as_uint(rm), __float_as_uint(rm), false, false);
        rm = fmaxf(__uint_as_float(rr.x), __uint_as_float(rr.y));
    }
    if (!__all(rm <= mOld + THR)) {   // T13 defer-max
        const float mN = fmaxf(mOld, rm);
        const float corr = exp2f((mOld - mN) * kE);
#pragma unroll
        for (int r = 0; r < 16; ++r) { oA[r] *= corr; oB[r] *= corr; }
        lSum *= corr;
        mOld = mN;
    }
    const float nmk = -mOld * kE;
#pragma unroll
    for (int r = 0; r < 16; ++r) s0[r] = exp2f(fmaf(s0[r], kE, nmk));
    if (two) {
#pragma unroll
        for (int r = 0; r < 16; ++r) s1[r] = exp2f(fmaf(s1[r], kE, nmk));
    }
    float rs = s0[0];
#pragma unroll
    for (int r = 1; r < 16; ++r) rs += s0[r];
    if (two) {
#pragma unroll
        for (int r = 0; r < 16; ++r) rs += s1[r];
    }
    {
        u32x2_t rr = __builtin_amdgcn_permlane32_swap(
            __float_as_uint(rs), __float_as_uint(rs), false, false);
        rs = __uint_as_float(rr.x) + __uint_as_float(rr.y);
    }
    lSum += rs;

    // ---- pack P (T12) + PV subtile 0 (kv-slices 0,1)
    {
        unsigned pk_[8];
#pragma unroll
        for (int i = 0; i < 8; ++i) pk_[i] = pack2(s0[2 * i], s0[2 * i + 1]);
        union { unsigned u[4]; bf16x8_t v; } W0, W1;
        u32x2_t ra = __builtin_amdgcn_permlane32_swap(pk_[0], pk_[2], false, false);
        u32x2_t rb = __builtin_amdgcn_permlane32_swap(pk_[1], pk_[3], false, false);
        W0.u[0] = ra.x; W0.u[1] = rb.x; W0.u[2] = ra.y; W0.u[3] = rb.y;
        u32x2_t rc = __builtin_amdgcn_permlane32_swap(pk_[4], pk_[6], false, false);
        u32x2_t rd = __builtin_amdgcn_permlane32_swap(pk_[5], pk_[7], false, false);
        W1.u[0] = rc.x; W1.u[1] = rd.x; W1.u[2] = rc.y; W1.u[3] = rd.y;
#pragma unroll
        for (int m = 0; m < 2; ++m) {
            const int kcol = 16 * m + hi8;
            bf16x8_t vf0 = ldsv8(V_ + l31 * 64 + (kcol ^ swzk));
            oA = __builtin_amdgcn_mfma_f32_32x32x16_bf16(vf0, m ? W1.v : W0.v, oA, 0, 0, 0);
            bf16x8_t vf1 = ldsv8(V_ + (32 + l31) * 64 + (kcol ^ swzk));
            oB = __builtin_amdgcn_mfma_f32_32x32x16_bf16(vf1, m ? W1.v : W0.v, oB, 0, 0, 0);
        }
    }
    // ---- PV subtile 1 (kv-slices 2,3)
    if (two) {
        unsigned pk_[8];
#pragma unroll
        for (int i = 0; i < 8; ++i) pk_[i] = pack2(s1[2 * i], s1[2 * i + 1]);
        union { unsigned u[4]; bf16x8_t v; } W0, W1;
        u32x2_t ra = __builtin_amdgcn_permlane32_swap(pk_[0], pk_[2], false, false);
        u32x2_t rb = __builtin_amdgcn_permlane32_swap(pk_[1], pk_[3], false, false);
        W0.u[0] = ra.x; W0.u[1] = rb.x; W0.u[2] = ra.y; W0.u[3] = rb.y;
        u32x2_t rc = __builtin_amdgcn_permlane32_swap(pk_[4], pk_[6], false, false);
        u32x2_t rd = __builtin_amdgcn_permlane32_swap(pk_[5], pk_[7], false, false);
        W1.u[0] = rc.x; W1.u[1] = rd.x; W1.u[2] = rc.y; W1.u[3] = rd.y;
#pragma unroll
        for (int m = 0; m < 2; ++m) {
            const int kcol = 16 * (2 + m) + hi8;
            bf16x8_t vf0 = ldsv8(V_ + l31 * 64 + (kcol ^ swzk));
            oA = __builtin_amdgcn_mfma_f32_32x32x16_bf16(vf0, m ? W1.v : W0.v, oA, 0, 0, 0);
            bf16x8_t vf1 = ldsv8(V_ + (32 + l31) * 64 + (kcol ^ swzk));
            oB = __builtin_amdgcn_mfma_f32_32x32x16_bf16(vf1, m ? W1.v : W0.v, oB, 0, 0, 0);
        }
    }
}

// ---------------------------------------------------------------- flash attention (causal) v5
// Complementary q-tile pairing: block bx owns q-tiles qLo=bx and qHi=7-bx -> every
// block does exactly 36 kv-tile computes (perfect balance), grid (4,64)=256=1/CU.
// Both q-tiles share one KV stream, processed interleaved per kv tile.
__global__ __launch_bounds__(512, 1) void attn_flash(
    const bf16* __restrict__ QKV, const bf16* __restrict__ VT,
    bf16* __restrict__ O)
{
    __shared__ bf16 Ks[2][64 * 64];   // K tile [kv][hs], XOR-swizzled
    __shared__ bf16 Vs[2][64 * 64];   // V^T tile [hs][kv], XOR-swizzled

    const int tid = threadIdx.x;
    const int w   = tid >> 6;
    const int ln  = tid & 63;
    const int l31 = ln & 31;
    const int hi  = ln >> 5;
    const int hi8 = hi << 3;

    const int qLo = blockIdx.x;        // 0..3
    const int qHi = 7 - qLo;           // 7..4
    const int bh = blockIdx.y;
    const long rowBase = (long)(bh >> 4) * T_;
    const int colBase = (bh & 15) * HS_;

    const int qabsL = qLo * 256 + w * 32 + l31;
    const int qabsH = qHi * 256 + w * 32 + l31;
    const int ct_L  = qLo * 4 + (w >> 1);    // qLo wave's diagonal kv tile
    const int ct_H  = qHi * 4 + (w >> 1);    // qHi wave's diagonal kv tile
    const int ctb   = qHi * 4 + 3;           // last kv tile staged by block

    // Q fragments (B-operand): lane holds Q[q][hs = 16s + hi8 + j]
    bf16x8_t qfL[4], qfH[4];
    {
        const bf16* qpL = QKV + (rowBase + qabsL) * QKV_LD + colBase + hi8;
        const bf16* qpH = QKV + (rowBase + qabsH) * QKV_LD + colBase + hi8;
#pragma unroll
        for (int s = 0; s < 4; ++s) {
            qfL[s] = *(const bf16x8_t*)(qpL + 16 * s);
            qfH[s] = *(const bf16x8_t*)(qpH + 16 * s);
        }
    }

    f32x16_t oLA = {}, oLB = {}, oHA = {}, oHB = {};
    float mL = -1e30f, lL = 0.f, mH = -1e30f, lH = 0.f;

    // staging: thread t -> row t>>3, chunk pre-swizzled so linear LDS write lands swizzled
    const int srow = tid >> 3;
    const int schunk = (((tid & 7) ^ (srow & 7)) << 3);
    const bf16* kSrc = QKV + (rowBase + srow) * QKV_LD + 1024 + colBase + schunk;
    const bf16* vSrc = VT + ((long)bh * HS_ + srow) * T_ + schunk;

    gload_lds16(kSrc, &Ks[0][w * 512]);
    gload_lds16(vSrc, &Vs[0][w * 512]);

    const int swzk = (l31 & 7) << 3;

    for (int c = 0; c <= ctb; ++c) {
        const int cur = c & 1;
        __syncthreads();   // buf[cur] staged (barrier drains vmcnt), prev reads done

        if (c < ctb) {     // prefetch next tile
            gload_lds16(kSrc + (long)(c + 1) * 64 * QKV_LD, &Ks[cur ^ 1][w * 512]);
            gload_lds16(vSrc + (c + 1) * 64, &Vs[cur ^ 1][w * 512]);
        }

        const bf16* K_ = Ks[cur];
        const bf16* V_ = Vs[cur];
        if (c <= ct_H)
            attn_tile(K_, V_, qfH, oHA, oHB, mH, lH, c, ct_H, qabsH, w, l31, hi, hi8, swzk);
        if (c <= ct_L)
            attn_tile(K_, V_, qfL, oLA, oLB, mL, lL, c, ct_L, qabsL, w, l31, hi, hi8, swzk);
    }

    // ---- normalize + store both q-tiles: reg r -> hs = (r&3)+8*(r>>2)+4*hi
    {
        const float inv = 1.f / lH;
        bf16* Op = O + (rowBase + qabsH) * D_ + colBase;
#pragma unroll
        for (int g = 0; g < 4; ++g) {
            u32x2_t sA, sB;
            sA.x = pack2(oHA[4 * g + 0] * inv, oHA[4 * g + 1] * inv);
            sA.y = pack2(oHA[4 * g + 2] * inv, oHA[4 * g + 3] * inv);
            sB.x = pack2(oHB[4 * g + 0] * inv, oHB[4 * g + 1] * inv);
            sB.y = pack2(oHB[4 * g + 2] * inv, oHB[4 * g + 3] * inv);
            *(u32x2_t*)(Op + 8 * g + 4 * hi)      = sA;
            *(u32x2_t*)(Op + 32 + 8 * g + 4 * hi) = sB;
        }
    }
    {
        const float inv = 1.f / lL;
        bf16* Op = O + (rowBase + qabsL) * D_ + colBase;
#pragma unroll
        for (int g = 0; g < 4; ++g) {
            u32x2_t sA, sB;
            sA.x = pack2(oLA[4 * g + 0] * inv, oLA[4 * g + 1] * inv);
            sA.y = pack2(oLA[4 * g + 2] * inv, oLA[4 * g + 3] * inv);
            sB.x = pack2(oLB[4 * g + 0] * inv, oLB[4 * g + 1] * inv);
            sB.y = pack2(oLB[4 * g + 2] * inv, oLB[4 * g + 3] * inv);
            *(u32x2_t*)(Op + 8 * g + 4 * hi)      = sA;
            *(u32x2_t*)(Op + 32 + 8 * g + 4 * hi) = sB;
        }
    }
}

// ---------------------------------------------------------------- launch
extern "C" void kernel_launch(void* const* d_in, const int* in_sizes, int n_in,
                              void* d_out, int out_size, void* d_ws, size_t ws_size,
                              hipStream_t stream)
{
    (void)in_sizes; (void)n_in; (void)out_size; (void)ws_size;
    const float* x   = (const float*)d_in[0];
    const float* wq  = (const float*)d_in[1];
    const float* wk  = (const float*)d_in[2];
    const float* wv  = (const float*)d_in[3];
    const float* wo  = (const float*)d_in[4];
    const float* bo  = (const float*)d_in[5];
    const float* w1  = (const float*)d_in[6];
    const float* b1  = (const float*)d_in[7];
    const float* w2  = (const float*)d_in[8];
    const float* b2  = (const float*)d_in[9];
    const float* g1  = (const float*)d_in[10];
    const float* be1 = (const float*)d_in[11];
    const float* g2  = (const float*)d_in[12];
    const float* be2 = (const float*)d_in[13];
    float* out = (float*)d_out;

    char* ws = (char*)d_ws;
    const size_t SLOT = (size_t)8192 * 1024 * 2;   // 16MB
    bf16* xn     = (bf16*)(ws);
    bf16* attnb  = (bf16*)(ws);
    bf16* qkv    = (bf16*)(ws + SLOT);
    bf16* xn2    = (bf16*)(ws + SLOT);
    bf16* vtb    = (bf16*)(ws + 4 * SLOT);
    bf16* hidden = (bf16*)(ws + 2 * SLOT);
    float* x1    = (float*)(ws + 6 * SLOT);
    char* wpos   = ws + 6 * SLOT + (size_t)33554432;
    bf16* wqkvT = (bf16*)(wpos);
    bf16* wqT = (bf16*)(wpos);
    bf16* wkT = (bf16*)(wpos + (size_t)2097152);
    bf16* wvT = (bf16*)(wpos + (size_t)2 * 2097152);
    bf16* woT = (bf16*)(wpos + (size_t)3 * 2097152);
    bf16* w1T = (bf16*)(wpos + (size_t)4 * 2097152);
    bf16* w2T = (bf16*)(wpos + (size_t)4 * 2097152 + 8388608);

    transpose_cvt<<<dim3(1024), 256, 0, stream>>>(wq, wqT, 1024, 1024);
    transpose_cvt<<<dim3(1024), 256, 0, stream>>>(wk, wkT, 1024, 1024);
    transpose_cvt<<<dim3(1024), 256, 0, stream>>>(wv, wvT, 1024, 1024);
    transpose_cvt<<<dim3(1024), 256, 0, stream>>>(wo, woT, 1024, 1024);
    transpose_cvt<<<dim3(4096), 256, 0, stream>>>(w1, w1T, 1024, 4096);
    transpose_cvt<<<dim3(4096), 256, 0, stream>>>(w2, w2T, 4096, 1024);

    ln_k<<<8192, 256, 0, stream>>>(x, g1, be1, xn);

    gemm2<0, 0, 0, 1><<<768, 512, 0, stream>>>(xn, wqkvT, nullptr, nullptr, qkv, 8192, 3072, 1024);

    vhead_transpose<<<8192, 256, 0, stream>>>(qkv, vtb);

    attn_flash<<<dim3(4, 64), 512, 0, stream>>>(qkv, vtb, attnb);

    gemm2<1, 0, 1, 0><<<256, 512, 0, stream>>>(attnb, woT, bo, x, x1, 8192, 1024, 1024);

    ln_k<<<8192, 256, 0, stream>>>(x1, g2, be2, xn2);

    gemm2<1, 1, 0, 1><<<1024, 512, 0, stream>>>(xn2, w1T, b1, nullptr, hidden, 8192, 4096, 1024);

    gemm2<1, 0, 1, 0><<<256, 512, 0, stream>>>(hidden, w2T, b2, x1, out, 8192, 1024, 4096);
}